// Round 5
// baseline (433.976 us; speedup 1.0000x reference)
//
#include <hip/hip_runtime.h>
#include <hip/hip_bf16.h>
#include <math.h>

typedef __bf16 bf16;
typedef __bf16 bf16x8 __attribute__((ext_vector_type(8)));
typedef __bf16 bf16x4 __attribute__((ext_vector_type(4)));
typedef float floatx4 __attribute__((ext_vector_type(4)));

#define B_ 2
#define T_ 2048
#define C_ 1024
#define H_ 16
#define HD_ 64

// async global->LDS, 16B per lane; lds dest = uniform base + lane*16
__device__ __forceinline__ void gload_lds16(const bf16* g, bf16* l) {
    __builtin_amdgcn_global_load_lds(
        (const __attribute__((address_space(1))) unsigned int*)(g),
        (__attribute__((address_space(3))) unsigned int*)(l), 16, 0, 0);
}

// ---------------------------------------------------------------------------
// Transpose + cast fp32 (K,N) -> bf16 (N,K)
// ---------------------------------------------------------------------------
__global__ void transpose_cast_kernel(const float* __restrict__ in, bf16* __restrict__ out,
                                      int K, int N) {
    __shared__ float tile[32][33];
    int kt = blockIdx.y * 32, nt = blockIdx.x * 32;
    int tx = threadIdx.x, ty = threadIdx.y;  // 32 x 8
    #pragma unroll
    for (int i = 0; i < 32; i += 8)
        tile[ty + i][tx] = in[(size_t)(kt + ty + i) * N + nt + tx];
    __syncthreads();
    #pragma unroll
    for (int i = 0; i < 32; i += 8)
        out[(size_t)(nt + ty + i) * K + kt + tx] = (bf16)tile[tx][ty + i];
}

// ---------------------------------------------------------------------------
// LayerNorm over C=1024. One block (256 threads) per row; 4 floats/thread.
// ---------------------------------------------------------------------------
__global__ __launch_bounds__(256) void ln_kernel(const float* __restrict__ x,
                                                 const float* __restrict__ g,
                                                 const float* __restrict__ b,
                                                 bf16* __restrict__ out_b,
                                                 float* __restrict__ out_f) {
    int row = blockIdx.x;
    int tid = threadIdx.x;
    const float* xr = x + (size_t)row * C_;
    float4 v = ((const float4*)xr)[tid];
    float s  = v.x + v.y + v.z + v.w;
    float ss = v.x * v.x + v.y * v.y + v.z * v.z + v.w * v.w;
    #pragma unroll
    for (int off = 32; off; off >>= 1) {
        s  += __shfl_down(s, off);
        ss += __shfl_down(ss, off);
    }
    __shared__ float red[8];
    int wid = tid >> 6;
    if ((tid & 63) == 0) { red[wid] = s; red[wid + 4] = ss; }
    __syncthreads();
    s  = red[0] + red[1] + red[2] + red[3];
    ss = red[4] + red[5] + red[6] + red[7];
    float mean = s * (1.0f / C_);
    float var  = ss * (1.0f / C_) - mean * mean;
    float rstd = rsqrtf(var + 1e-5f);
    float4 gv = ((const float4*)g)[tid];
    float4 bv = ((const float4*)b)[tid];
    float o0 = (v.x - mean) * rstd * gv.x + bv.x;
    float o1 = (v.y - mean) * rstd * gv.y + bv.y;
    float o2 = (v.z - mean) * rstd * gv.z + bv.z;
    float o3 = (v.w - mean) * rstd * gv.w + bv.w;
    bf16x4 ob = { (bf16)o0, (bf16)o1, (bf16)o2, (bf16)o3 };
    ((bf16x4*)out_b)[(size_t)row * 256 + tid] = ob;
    if (out_f) {
        float4 of; of.x = o0; of.y = o1; of.z = o2; of.w = o3;
        ((float4*)out_f)[(size_t)row * 256 + tid] = of;
    }
}

// ---------------------------------------------------------------------------
// m97-structure GEMM (wide N): C = A @ Bt^T, 128x128 tile, 256 thr = 4 waves.
// MODE: 0 = bias, bf16 out; 1 = bias+gelu, bf16 out.
// ---------------------------------------------------------------------------
__device__ __forceinline__ float gelu_exact(float v) {
    return 0.5f * v * (1.0f + erff(v * 0.70710678118654752f));
}

template<int TN, int MODE>
__global__ __launch_bounds__(256) void gemm128(const bf16* __restrict__ A,
                                               const bf16* __restrict__ Bt,
                                               const float* __restrict__ bias,
                                               const float* __restrict__ add,
                                               void* __restrict__ out,
                                               int M, int N, int K) {
    constexpr int BN = TN / 32;           // n-tiles per wave
    __shared__ __align__(16) bf16 As[128 * 64];
    __shared__ __align__(16) bf16 Bs[TN * 64];

    int m0 = blockIdx.y * 128, n0 = blockIdx.x * TN;
    int tid = threadIdx.x;
    int wid = __builtin_amdgcn_readfirstlane(tid >> 6);
    int lane = tid & 63;
    int lm = lane & 15, quad = lane >> 4;
    int wm = (wid & 1) * 64;
    int wn = (wid >> 1) * (TN / 2);
    int lrow = lane >> 3;                 // 0..7
    int lcol = (lane & 7) * 8;

    const bf16* Ablk = A  + (size_t)m0 * K;
    const bf16* Bblk = Bt + (size_t)n0 * K;

    floatx4 acc[4][BN];
    #pragma unroll
    for (int i = 0; i < 4; i++)
        #pragma unroll
        for (int j = 0; j < BN; j++) { floatx4 z = {0.f, 0.f, 0.f, 0.f}; acc[i][j] = z; }

    for (int k0 = 0; k0 < K; k0 += 64) {
        __syncthreads();   // prior iteration's LDS reads complete
        #pragma unroll
        for (int c = 0; c < 4; c++) {
            int row = wid * 32 + c * 8;
            gload_lds16(Ablk + (size_t)(row + lrow) * K + k0 + lcol, As + row * 64);
        }
        #pragma unroll
        for (int c = 0; c < TN / 32; c++) {
            int row = wid * (TN / 4) + c * 8;
            gload_lds16(Bblk + (size_t)(row + lrow) * K + k0 + lcol, Bs + row * 64);
        }
        __syncthreads();   // staged data visible (compiler drains vmcnt)
        #pragma unroll
        for (int kc = 0; kc < 2; kc++) {
            bf16x8 af[4], bfr[BN];
            #pragma unroll
            for (int i = 0; i < 4; i++)
                af[i] = *(const bf16x8*)(As + (wm + i * 16 + lm) * 64 + kc * 32 + quad * 8);
            #pragma unroll
            for (int j = 0; j < BN; j++)
                bfr[j] = *(const bf16x8*)(Bs + (wn + j * 16 + lm) * 64 + kc * 32 + quad * 8);
            #pragma unroll
            for (int i = 0; i < 4; i++)
                #pragma unroll
                for (int j = 0; j < BN; j++)
                    acc[i][j] = __builtin_amdgcn_mfma_f32_16x16x32_bf16(af[i], bfr[j], acc[i][j], 0, 0, 0);
        }
    }

    #pragma unroll
    for (int i = 0; i < 4; i++)
        #pragma unroll
        for (int j = 0; j < BN; j++) {
            int mbase = m0 + wm + i * 16 + quad * 4;
            int n     = n0 + wn + j * 16 + lm;
            float bsn = bias[n];
            #pragma unroll
            for (int r = 0; r < 4; r++) {
                size_t idx = (size_t)(mbase + r) * N + n;
                float v = acc[i][j][r] + bsn;
                if (MODE == 1) v = gelu_exact(v);
                if (MODE == 2) { ((float*)out)[idx] = v + add[idx]; }
                else           { ((bf16*)out)[idx] = (bf16)v; }
            }
        }
}

// ---------------------------------------------------------------------------
// Narrow-N GEMM: 128x128 tile, 512 thr = 8 waves (wave-tile 32x64, 2 waves/SIMD).
// Grid (N/128, M/128) = 256 blocks -> 1 block/CU, no tail.
// MODE 2: bias + add, f32 out.
// ---------------------------------------------------------------------------
template<int MODE>
__global__ __launch_bounds__(512) void gemm_w8(const bf16* __restrict__ A,
                                               const bf16* __restrict__ Bt,
                                               const float* __restrict__ bias,
                                               const float* __restrict__ add,
                                               void* __restrict__ out,
                                               int M, int N, int K) {
    __shared__ __align__(16) bf16 As[128 * 64];
    __shared__ __align__(16) bf16 Bs[128 * 64];

    int m0 = blockIdx.y * 128, n0 = blockIdx.x * 128;
    int tid = threadIdx.x;
    int wid = __builtin_amdgcn_readfirstlane(tid >> 6);   // 0..7
    int lane = tid & 63;
    int lm = lane & 15, quad = lane >> 4;
    int wm = (wid & 3) * 32;
    int wn = (wid >> 2) * 64;
    int lrow = lane >> 3;                 // 0..7
    int lcol = (lane & 7) * 8;

    const bf16* Ablk = A  + (size_t)m0 * K;
    const bf16* Bblk = Bt + (size_t)n0 * K;

    floatx4 acc[2][4];
    #pragma unroll
    for (int i = 0; i < 2; i++)
        #pragma unroll
        for (int j = 0; j < 4; j++) { floatx4 z = {0.f, 0.f, 0.f, 0.f}; acc[i][j] = z; }

    for (int k0 = 0; k0 < K; k0 += 64) {
        __syncthreads();
        #pragma unroll
        for (int c = 0; c < 2; c++) {
            int row = wid * 16 + c * 8;
            gload_lds16(Ablk + (size_t)(row + lrow) * K + k0 + lcol, As + row * 64);
        }
        #pragma unroll
        for (int c = 0; c < 2; c++) {
            int row = wid * 16 + c * 8;
            gload_lds16(Bblk + (size_t)(row + lrow) * K + k0 + lcol, Bs + row * 64);
        }
        __syncthreads();
        #pragma unroll
        for (int kc = 0; kc < 2; kc++) {
            bf16x8 af[2], bfr[4];
            #pragma unroll
            for (int i = 0; i < 2; i++)
                af[i] = *(const bf16x8*)(As + (wm + i * 16 + lm) * 64 + kc * 32 + quad * 8);
            #pragma unroll
            for (int j = 0; j < 4; j++)
                bfr[j] = *(const bf16x8*)(Bs + (wn + j * 16 + lm) * 64 + kc * 32 + quad * 8);
            #pragma unroll
            for (int i = 0; i < 2; i++)
                #pragma unroll
                for (int j = 0; j < 4; j++)
                    acc[i][j] = __builtin_amdgcn_mfma_f32_16x16x32_bf16(af[i], bfr[j], acc[i][j], 0, 0, 0);
        }
    }

    #pragma unroll
    for (int i = 0; i < 2; i++)
        #pragma unroll
        for (int j = 0; j < 4; j++) {
            int mbase = m0 + wm + i * 16 + quad * 4;
            int n     = n0 + wn + j * 16 + lm;
            float bsn = bias[n];
            #pragma unroll
            for (int r = 0; r < 4; r++) {
                size_t idx = (size_t)(mbase + r) * N + n;
                float v = acc[i][j][r] + bsn;
                if (MODE == 1) v = gelu_exact(v);
                if (MODE == 2) { ((float*)out)[idx] = v + add[idx]; }
                else           { ((bf16*)out)[idx] = (bf16)v; }
            }
        }
}

// ---------------------------------------------------------------------------
// Flash attention, MFMA, S^T formulation (see R4 notes).
// ---------------------------------------------------------------------------
#define QT_ 128
#define KT_ 64

__global__ __launch_bounds__(256) void attn_mfma_kernel(const bf16* __restrict__ qkv,
                                                        bf16* __restrict__ o) {
    int bh = blockIdx.x;
    int b = bh >> 4, h = bh & 15;
    int q0 = (gridDim.y - 1 - blockIdx.y) * QT_;   // heavy-first
    int tid = threadIdx.x, wid = tid >> 6, lane = tid & 63;
    int wm = wid * 32;
    int lm = lane & 15, quad = lane >> 4;
    int sw = lm & 7;

    const bf16* base = qkv + (size_t)b * T_ * (3 * C_) + h * (3 * HD_);

    __shared__ __align__(16) bf16 Ks[KT_][72];      // K rows [key][d]
    __shared__ __align__(16) bf16 Vt[HD_][72];      // V^T [d][key-swizzled]
    __shared__ __align__(16) bf16 PsT[4][32][64];   // per-wave P [qrow][key-swizzled]

    bf16x8 qf[2][2];  // [am][kc]  (B-operand: lane lm = q-row)
    #pragma unroll
    for (int am = 0; am < 2; am++)
        #pragma unroll
        for (int kc = 0; kc < 2; kc++) {
            int r = q0 + wm + am * 16 + lm;
            qf[am][kc] = *(const bf16x8*)(base + (size_t)r * (3 * C_) + kc * 32 + quad * 8);
        }

    floatx4 acc_o[2][4];
    #pragma unroll
    for (int am = 0; am < 2; am++)
        #pragma unroll
        for (int dn = 0; dn < 4; dn++) { floatx4 z = {0.f, 0.f, 0.f, 0.f}; acc_o[am][dn] = z; }
    float mst[2] = { -1e30f, -1e30f };
    float lst[2] = { 0.0f, 0.0f };

    int scol = (tid & 7) * 8;

    int kmax = q0 + QT_;
    for (int k0 = 0; k0 < kmax; k0 += KT_) {
        int kr0 = tid >> 3;               // 0..31
        bf16x8 kv0 = *(const bf16x8*)(base + (size_t)(k0 + kr0)      * (3 * C_) + HD_ + scol);
        bf16x8 kv1 = *(const bf16x8*)(base + (size_t)(k0 + kr0 + 32) * (3 * C_) + HD_ + scol);
        bf16x8 vv0 = *(const bf16x8*)(base + (size_t)(k0 + kr0)      * (3 * C_) + 2 * HD_ + scol);
        bf16x8 vv1 = *(const bf16x8*)(base + (size_t)(k0 + kr0 + 32) * (3 * C_) + 2 * HD_ + scol);
        __syncthreads();
        *(bf16x8*)(&Ks[kr0][scol])      = kv0;
        *(bf16x8*)(&Ks[kr0 + 32][scol]) = kv1;
        {
            int c = scol >> 3;
            int pk0 = (((kr0)       >> 3) ^ c) * 8 + (kr0 & 7);
            int pk1 = (((kr0 + 32)  >> 3) ^ c) * 8 + (kr0 & 7);
            #pragma unroll
            for (int j = 0; j < 8; j++) {
                Vt[scol + j][pk0] = vv0[j];
                Vt[scol + j][pk1] = vv1[j];
            }
        }
        __syncthreads();

        if (k0 <= q0 + wm + 31) {
            floatx4 st[4][2];
            #pragma unroll
            for (int bn = 0; bn < 4; bn++)
                #pragma unroll
                for (int am = 0; am < 2; am++) { floatx4 z = {0.f, 0.f, 0.f, 0.f}; st[bn][am] = z; }
            #pragma unroll
            for (int kc = 0; kc < 2; kc++) {
                bf16x8 kf[4];
                #pragma unroll
                for (int bn = 0; bn < 4; bn++)
                    kf[bn] = *(const bf16x8*)(&Ks[bn * 16 + lm][kc * 32 + quad * 8]);
                #pragma unroll
                for (int bn = 0; bn < 4; bn++)
                    #pragma unroll
                    for (int am = 0; am < 2; am++)
                        st[bn][am] = __builtin_amdgcn_mfma_f32_16x16x32_bf16(kf[bn], qf[am][kc], st[bn][am], 0, 0, 0);
            }

            float alpha_s[2];
            #pragma unroll
            for (int am = 0; am < 2; am++) {
                int gq = q0 + wm + am * 16 + lm;           // this lane's q-row
                int need_mask = (k0 + KT_ - 1) > (q0 + wm + am * 16);
                float vv[4][4];
                float rm = -1e30f;
                #pragma unroll
                for (int bn = 0; bn < 4; bn++)
                    #pragma unroll
                    for (int r = 0; r < 4; r++) {
                        float sv = st[bn][am][r] * 0.125f;  // 1/sqrt(64)
                        int key = k0 + bn * 16 + quad * 4 + r;
                        sv = (!need_mask || key <= gq) ? sv : -1e30f;
                        vv[bn][r] = sv;
                        rm = fmaxf(rm, sv);
                    }
                rm = fmaxf(rm, __shfl_xor(rm, 16));
                rm = fmaxf(rm, __shfl_xor(rm, 32));
                float mold = mst[am];
                float mnew = fmaxf(mold, rm);
                float alpha = __expf(mold - mnew);
                mst[am] = mnew;
                float ps = 0.f;
                #pragma unroll
                for (int bn = 0; bn < 4; bn++) {
                    float p0 = __expf(vv[bn][0] - mnew);
                    float p1 = __expf(vv[bn][1] - mnew);
                    float p2 = __expf(vv[bn][2] - mnew);
                    float p3 = __expf(vv[bn][3] - mnew);
                    ps += (p0 + p1) + (p2 + p3);
                    bf16x4 pk = { (bf16)p0, (bf16)p1, (bf16)p2, (bf16)p3 };
                    int kb = bn * 2 + (quad >> 1);
                    int col = ((kb ^ sw) << 3) + (quad & 1) * 4;
                    *(bf16x4*)(&PsT[wid][am * 16 + lm][col]) = pk;
                }
                ps += __shfl_xor(ps, 16);
                ps += __shfl_xor(ps, 32);
                lst[am] = lst[am] * alpha + ps;
                alpha_s[am] = alpha;
            }

            #pragma unroll
            for (int am = 0; am < 2; am++)
                #pragma unroll
                for (int r = 0; r < 4; r++) {
                    float ar = __shfl(alpha_s[am], quad * 4 + r);
                    #pragma unroll
                    for (int dn = 0; dn < 4; dn++) acc_o[am][dn][r] *= ar;
                }

            __asm__ volatile("s_waitcnt lgkmcnt(0)" ::: "memory");

            #pragma unroll
            for (int kc = 0; kc < 2; kc++) {
                bf16x8 pa[2], vfr[4];
                #pragma unroll
                for (int am = 0; am < 2; am++)
                    pa[am] = *(const bf16x8*)(&PsT[wid][am * 16 + lm][((kc * 4 + quad) ^ sw) << 3]);
                #pragma unroll
                for (int dn = 0; dn < 4; dn++) {
                    int d = dn * 16 + lm;
                    int swd = (d >> 3) & 7;
                    vfr[dn] = *(const bf16x8*)(&Vt[d][(((kc * 4 + quad) ^ swd) << 3)]);
                }
                #pragma unroll
                for (int am = 0; am < 2; am++)
                    #pragma unroll
                    for (int dn = 0; dn < 4; dn++)
                        acc_o[am][dn] = __builtin_amdgcn_mfma_f32_16x16x32_bf16(pa[am], vfr[dn], acc_o[am][dn], 0, 0, 0);
            }
        }
    }

    #pragma unroll
    for (int am = 0; am < 2; am++) {
        float il = 1.0f / lst[am];
        #pragma unroll
        for (int r = 0; r < 4; r++) {
            float ir = __shfl(il, quad * 4 + r);
            int qrow = q0 + wm + am * 16 + quad * 4 + r;
            bf16* orow = o + ((size_t)b * T_ + qrow) * C_ + h * HD_;
            #pragma unroll
            for (int dn = 0; dn < 4; dn++)
                orow[dn * 16 + lm] = (bf16)(acc_o[am][dn][r] * ir);
        }
    }
}

// ---------------------------------------------------------------------------
extern "C" void kernel_launch(void* const* d_in, const int* in_sizes, int n_in,
                              void* d_out, int out_size, void* d_ws, size_t ws_size,
                              hipStream_t stream) {
    (void)in_sizes; (void)n_in; (void)out_size; (void)ws_size;
    const float* x      = (const float*)d_in[0];
    const float* ln1_g  = (const float*)d_in[1];
    const float* ln1_b  = (const float*)d_in[2];
    const float* ln2_g  = (const float*)d_in[3];
    const float* ln2_b  = (const float*)d_in[4];
    const float* w_in   = (const float*)d_in[5];
    const float* b_in   = (const float*)d_in[6];
    const float* w_out  = (const float*)d_in[7];
    const float* b_out  = (const float*)d_in[8];
    const float* w_fc   = (const float*)d_in[9];
    const float* b_fc   = (const float*)d_in[10];
    const float* w_proj = (const float*)d_in[11];
    const float* b_proj = (const float*)d_in[12];

    char* ws = (char*)d_ws;
    const size_t MB = 1024 * 1024;
    bf16*  w_inT   = (bf16*)(ws + 0);        // 6 MB
    bf16*  w_outT  = (bf16*)(ws + 6 * MB);   // 2 MB
    bf16*  w_fcT   = (bf16*)(ws + 8 * MB);   // 8 MB
    bf16*  w_projT = (bf16*)(ws + 16 * MB);  // 8 MB
    bf16*  qkv     = (bf16*)(ws + 24 * MB);  // 24 MB (shares 32MB region with fc_act)
    bf16*  fc_act  = (bf16*)(ws + 24 * MB);  // 32 MB
    bf16*  o_buf   = (bf16*)(ws + 56 * MB);  // 8 MB (shares with y_b)
    bf16*  y_b     = (bf16*)(ws + 56 * MB);  // 8 MB
    bf16*  h_b     = (bf16*)(ws + 64 * MB);  // 8 MB (shares 16MB region with x1)
    float* x1      = (float*)(ws + 64 * MB); // 16 MB
    float* y_f     = (float*)(ws + 80 * MB); // 16 MB

    const int M = B_ * T_;  // 4096

    dim3 tb(32, 8);
    transpose_cast_kernel<<<dim3(3 * C_ / 32, C_ / 32), tb, 0, stream>>>(w_in,   w_inT,   C_,     3 * C_);
    transpose_cast_kernel<<<dim3(C_ / 32,     C_ / 32), tb, 0, stream>>>(w_out,  w_outT,  C_,     C_);
    transpose_cast_kernel<<<dim3(4 * C_ / 32, C_ / 32), tb, 0, stream>>>(w_fc,   w_fcT,   C_,     4 * C_);
    transpose_cast_kernel<<<dim3(C_ / 32, 4 * C_ / 32), tb, 0, stream>>>(w_proj, w_projT, 4 * C_, C_);

    ln_kernel<<<M, 256, 0, stream>>>(x, ln1_g, ln1_b, h_b, nullptr);
    gemm128<128, 0><<<dim3(3 * C_ / 128, M / 128), 256, 0, stream>>>(h_b, w_inT, b_in, nullptr,
                                                                     qkv, M, 3 * C_, C_);
    attn_mfma_kernel<<<dim3(B_ * H_, T_ / QT_), 256, 0, stream>>>(qkv, o_buf);
    gemm_w8<2><<<dim3(C_ / 128, M / 128), 512, 0, stream>>>(o_buf, w_outT, b_out, x,
                                                            x1, M, C_, C_);
    ln_kernel<<<M, 256, 0, stream>>>(x1, ln2_g, ln2_b, y_b, y_f);
    gemm128<128, 1><<<dim3(4 * C_ / 128, M / 128), 256, 0, stream>>>(y_b, w_fcT, b_fc, nullptr,
                                                                     fc_act, M, 4 * C_, C_);
    gemm_w8<2><<<dim3(C_ / 128, M / 128), 512, 0, stream>>>(fc_act, w_projT, b_proj, y_f,
                                                            (float*)d_out, M, C_, 4 * C_);
}

// Round 6
// 391.085 us; speedup vs baseline: 1.1097x; 1.1097x over previous
//
#include <hip/hip_runtime.h>
#include <hip/hip_bf16.h>
#include <math.h>

typedef __bf16 bf16;
typedef __bf16 bf16x8 __attribute__((ext_vector_type(8)));
typedef __bf16 bf16x4 __attribute__((ext_vector_type(4)));
typedef float floatx4 __attribute__((ext_vector_type(4)));

#define B_ 2
#define T_ 2048
#define C_ 1024
#define H_ 16
#define HD_ 64

// async global->LDS, 16B per lane; lds dest = uniform base + lane*16
__device__ __forceinline__ void gload_lds16(const bf16* g, bf16* l) {
    __builtin_amdgcn_global_load_lds(
        (const __attribute__((address_space(1))) unsigned int*)(g),
        (__attribute__((address_space(3))) unsigned int*)(l), 16, 0, 0);
}

// ---------------------------------------------------------------------------
// All four weight transposes in ONE launch (kill 3 launch gaps).
// fp32 (K,N) -> bf16 (N,K), 32x32 tiles, block (32,8).
// ---------------------------------------------------------------------------
__global__ void transpose_all(const float* __restrict__ w_in, const float* __restrict__ w_out,
                              const float* __restrict__ w_fc, const float* __restrict__ w_proj,
                              bf16* __restrict__ o_in, bf16* __restrict__ o_out,
                              bf16* __restrict__ o_fc, bf16* __restrict__ o_proj) {
    int t = blockIdx.x;
    const float* src; bf16* dst; int K, N, idx;
    if (t < 3072)      { src = w_in;   dst = o_in;   K = 1024; N = 3072; idx = t; }
    else if (t < 4096) { src = w_out;  dst = o_out;  K = 1024; N = 1024; idx = t - 3072; }
    else if (t < 8192) { src = w_fc;   dst = o_fc;   K = 1024; N = 4096; idx = t - 4096; }
    else               { src = w_proj; dst = o_proj; K = 4096; N = 1024; idx = t - 8192; }
    int ntx = N >> 5;
    int nt = (idx % ntx) * 32, kt = (idx / ntx) * 32;
    __shared__ float tile[32][33];
    int tx = threadIdx.x, ty = threadIdx.y;
    #pragma unroll
    for (int i = 0; i < 32; i += 8)
        tile[ty + i][tx] = src[(size_t)(kt + ty + i) * N + nt + tx];
    __syncthreads();
    #pragma unroll
    for (int i = 0; i < 32; i += 8)
        dst[(size_t)(nt + ty + i) * K + kt + tx] = (bf16)tile[tx][ty + i];
}

// ---------------------------------------------------------------------------
// LayerNorm over C=1024. One block (256 threads) per row; 4 floats/thread.
// ---------------------------------------------------------------------------
__global__ __launch_bounds__(256) void ln_kernel(const float* __restrict__ x,
                                                 const float* __restrict__ g,
                                                 const float* __restrict__ b,
                                                 bf16* __restrict__ out_b,
                                                 float* __restrict__ out_f) {
    int row = blockIdx.x;
    int tid = threadIdx.x;
    const float* xr = x + (size_t)row * C_;
    float4 v = ((const float4*)xr)[tid];
    float s  = v.x + v.y + v.z + v.w;
    float ss = v.x * v.x + v.y * v.y + v.z * v.z + v.w * v.w;
    #pragma unroll
    for (int off = 32; off; off >>= 1) {
        s  += __shfl_down(s, off);
        ss += __shfl_down(ss, off);
    }
    __shared__ float red[8];
    int wid = tid >> 6;
    if ((tid & 63) == 0) { red[wid] = s; red[wid + 4] = ss; }
    __syncthreads();
    s  = red[0] + red[1] + red[2] + red[3];
    ss = red[4] + red[5] + red[6] + red[7];
    float mean = s * (1.0f / C_);
    float var  = ss * (1.0f / C_) - mean * mean;
    float rstd = rsqrtf(var + 1e-5f);
    float4 gv = ((const float4*)g)[tid];
    float4 bv = ((const float4*)b)[tid];
    float o0 = (v.x - mean) * rstd * gv.x + bv.x;
    float o1 = (v.y - mean) * rstd * gv.y + bv.y;
    float o2 = (v.z - mean) * rstd * gv.z + bv.z;
    float o3 = (v.w - mean) * rstd * gv.w + bv.w;
    bf16x4 ob = { (bf16)o0, (bf16)o1, (bf16)o2, (bf16)o3 };
    ((bf16x4*)out_b)[(size_t)row * 256 + tid] = ob;
    if (out_f) {
        float4 of; of.x = o0; of.y = o1; of.z = o2; of.w = o3;
        ((float4*)out_f)[(size_t)row * 256 + tid] = of;
    }
}

// ---------------------------------------------------------------------------
// m97-structure GEMM (wide N): C = A @ Bt^T, 128xTN block tile, 256 thr = 4 waves.
// MODE: 0 = bias, bf16 out; 1 = bias+gelu, bf16 out; 2 = bias+add, f32 out.
// ---------------------------------------------------------------------------
__device__ __forceinline__ float gelu_exact(float v) {
    return 0.5f * v * (1.0f + erff(v * 0.70710678118654752f));
}

template<int TN, int MODE>
__global__ __launch_bounds__(256) void gemm128(const bf16* __restrict__ A,
                                               const bf16* __restrict__ Bt,
                                               const float* __restrict__ bias,
                                               const float* __restrict__ add,
                                               void* __restrict__ out,
                                               int M, int N, int K) {
    constexpr int BN = TN / 32;           // n-tiles per wave
    __shared__ __align__(16) bf16 As[128 * 64];
    __shared__ __align__(16) bf16 Bs[TN * 64];

    int m0 = blockIdx.y * 128, n0 = blockIdx.x * TN;
    int tid = threadIdx.x;
    int wid = __builtin_amdgcn_readfirstlane(tid >> 6);
    int lane = tid & 63;
    int lm = lane & 15, quad = lane >> 4;
    int wm = (wid & 1) * 64;
    int wn = (wid >> 1) * (TN / 2);
    int lrow = lane >> 3;                 // 0..7
    int lcol = (lane & 7) * 8;

    const bf16* Ablk = A  + (size_t)m0 * K;
    const bf16* Bblk = Bt + (size_t)n0 * K;

    floatx4 acc[4][BN];
    #pragma unroll
    for (int i = 0; i < 4; i++)
        #pragma unroll
        for (int j = 0; j < BN; j++) { floatx4 z = {0.f, 0.f, 0.f, 0.f}; acc[i][j] = z; }

    for (int k0 = 0; k0 < K; k0 += 64) {
        __syncthreads();   // prior iteration's LDS reads complete
        #pragma unroll
        for (int c = 0; c < 4; c++) {
            int row = wid * 32 + c * 8;
            gload_lds16(Ablk + (size_t)(row + lrow) * K + k0 + lcol, As + row * 64);
        }
        #pragma unroll
        for (int c = 0; c < TN / 32; c++) {
            int row = wid * (TN / 4) + c * 8;
            gload_lds16(Bblk + (size_t)(row + lrow) * K + k0 + lcol, Bs + row * 64);
        }
        __syncthreads();   // staged data visible (compiler drains vmcnt)
        #pragma unroll
        for (int kc = 0; kc < 2; kc++) {
            bf16x8 af[4], bfr[BN];
            #pragma unroll
            for (int i = 0; i < 4; i++)
                af[i] = *(const bf16x8*)(As + (wm + i * 16 + lm) * 64 + kc * 32 + quad * 8);
            #pragma unroll
            for (int j = 0; j < BN; j++)
                bfr[j] = *(const bf16x8*)(Bs + (wn + j * 16 + lm) * 64 + kc * 32 + quad * 8);
            #pragma unroll
            for (int i = 0; i < 4; i++)
                #pragma unroll
                for (int j = 0; j < BN; j++)
                    acc[i][j] = __builtin_amdgcn_mfma_f32_16x16x32_bf16(af[i], bfr[j], acc[i][j], 0, 0, 0);
        }
    }

    #pragma unroll
    for (int i = 0; i < 4; i++)
        #pragma unroll
        for (int j = 0; j < BN; j++) {
            int mbase = m0 + wm + i * 16 + quad * 4;
            int n     = n0 + wn + j * 16 + lm;
            float bsn = bias[n];
            #pragma unroll
            for (int r = 0; r < 4; r++) {
                size_t idx = (size_t)(mbase + r) * N + n;
                float v = acc[i][j][r] + bsn;
                if (MODE == 1) v = gelu_exact(v);
                if (MODE == 2) { ((float*)out)[idx] = v + add[idx]; }
                else           { ((bf16*)out)[idx] = (bf16)v; }
            }
        }
}

// ---------------------------------------------------------------------------
// Narrow-N GEMM (N=1024): TM=128, TN=64, 4 waves, DOUBLE-BUFFERED LDS with
// raw s_barrier + fine s_waitcnt vmcnt(6): this iter waits only on loads
// issued one iteration ago (grid is 2 blocks/CU -> no cross-block overlap to
// hide the usual barrier vmcnt(0) drain; counters R4/R5 show ~80% stall).
// 1D grid, XCD swizzle: xcd = lin%8 owns 4 M-strips -> A fetched ~once/XCD.
// Requires M/128 == 32. MODE 2: bias + add, f32 out.
// ---------------------------------------------------------------------------
template<int MODE>
__global__ __launch_bounds__(256) void gemm_nrw(const bf16* __restrict__ A,
                                                const bf16* __restrict__ Bt,
                                                const float* __restrict__ bias,
                                                const float* __restrict__ add,
                                                void* __restrict__ out,
                                                int M, int N, int K) {
    __shared__ __align__(16) bf16 As[2][128 * 64];
    __shared__ __align__(16) bf16 Bs[2][64 * 64];

    int lin = blockIdx.x;
    int xcd = lin & 7, loc = lin >> 3;
    int m0 = (((xcd << 2) | (loc & 3))) * 128;   // 4 M-strips per XCD
    int n0 = (loc >> 2) * 64;
    int tid = threadIdx.x;
    int wid = __builtin_amdgcn_readfirstlane(tid >> 6);
    int lane = tid & 63;
    int lm = lane & 15, quad = lane >> 4;
    int wm = (wid & 1) * 64;
    int wn = (wid >> 1) * 32;
    int lrow = lane >> 3;
    int lcol = (lane & 7) * 8;

    const bf16* Ablk = A  + (size_t)m0 * K;
    const bf16* Bblk = Bt + (size_t)n0 * K;

    floatx4 acc[4][2];
    #pragma unroll
    for (int i = 0; i < 4; i++)
        #pragma unroll
        for (int j = 0; j < 2; j++) { floatx4 z = {0.f, 0.f, 0.f, 0.f}; acc[i][j] = z; }

    // prologue: stage k=0 into buf 0 (6 loads/thread)
    #pragma unroll
    for (int c = 0; c < 4; c++) {
        int row = wid * 32 + c * 8;
        gload_lds16(Ablk + (size_t)(row + lrow) * K + lcol, &As[0][row * 64]);
    }
    #pragma unroll
    for (int c = 0; c < 2; c++) {
        int row = wid * 16 + c * 8;
        gload_lds16(Bblk + (size_t)(row + lrow) * K + lcol, &Bs[0][row * 64]);
    }

    int cur = 0;
    for (int k0 = 0; k0 < K; k0 += 64, cur ^= 1) {
        int nxt = cur ^ 1;
        if (k0 + 64 < K) {
            __builtin_amdgcn_s_barrier();           // readers of buf[nxt] (iter k-1) done
            __asm__ volatile("" ::: "memory");
            #pragma unroll
            for (int c = 0; c < 4; c++) {
                int row = wid * 32 + c * 8;
                gload_lds16(Ablk + (size_t)(row + lrow) * K + (k0 + 64) + lcol, &As[nxt][row * 64]);
            }
            #pragma unroll
            for (int c = 0; c < 2; c++) {
                int row = wid * 16 + c * 8;
                gload_lds16(Bblk + (size_t)(row + lrow) * K + (k0 + 64) + lcol, &Bs[nxt][row * 64]);
            }
            __asm__ volatile("s_waitcnt vmcnt(6)" ::: "memory");  // buf[cur] loads (1 iter old) done
        } else {
            __asm__ volatile("s_waitcnt vmcnt(0)" ::: "memory");
        }
        __builtin_amdgcn_s_barrier();               // all waves' buf[cur] ready
        __asm__ volatile("" ::: "memory");
        #pragma unroll
        for (int kc = 0; kc < 2; kc++) {
            bf16x8 af[4], bfr[2];
            #pragma unroll
            for (int i = 0; i < 4; i++)
                af[i] = *(const bf16x8*)(&As[cur][(wm + i * 16 + lm) * 64 + kc * 32 + quad * 8]);
            #pragma unroll
            for (int j = 0; j < 2; j++)
                bfr[j] = *(const bf16x8*)(&Bs[cur][(wn + j * 16 + lm) * 64 + kc * 32 + quad * 8]);
            #pragma unroll
            for (int i = 0; i < 4; i++)
                #pragma unroll
                for (int j = 0; j < 2; j++)
                    acc[i][j] = __builtin_amdgcn_mfma_f32_16x16x32_bf16(af[i], bfr[j], acc[i][j], 0, 0, 0);
        }
    }

    #pragma unroll
    for (int i = 0; i < 4; i++)
        #pragma unroll
        for (int j = 0; j < 2; j++) {
            int mbase = m0 + wm + i * 16 + quad * 4;
            int n     = n0 + wn + j * 16 + lm;
            float bsn = bias[n];
            #pragma unroll
            for (int r = 0; r < 4; r++) {
                size_t idx = (size_t)(mbase + r) * N + n;
                float v = acc[i][j][r] + bsn;
                if (MODE == 1) v = gelu_exact(v);
                if (MODE == 2) { ((float*)out)[idx] = v + add[idx]; }
                else           { ((bf16*)out)[idx] = (bf16)v; }
            }
        }
}

// ---------------------------------------------------------------------------
// Flash attention, MFMA, S^T formulation (see R4 notes).
// ---------------------------------------------------------------------------
#define QT_ 128
#define KT_ 64

__global__ __launch_bounds__(256) void attn_mfma_kernel(const bf16* __restrict__ qkv,
                                                        bf16* __restrict__ o) {
    int bh = blockIdx.x;
    int b = bh >> 4, h = bh & 15;
    int q0 = (gridDim.y - 1 - blockIdx.y) * QT_;   // heavy-first
    int tid = threadIdx.x, wid = tid >> 6, lane = tid & 63;
    int wm = wid * 32;
    int lm = lane & 15, quad = lane >> 4;
    int sw = lm & 7;

    const bf16* base = qkv + (size_t)b * T_ * (3 * C_) + h * (3 * HD_);

    __shared__ __align__(16) bf16 Ks[KT_][72];      // K rows [key][d]
    __shared__ __align__(16) bf16 Vt[HD_][72];      // V^T [d][key-swizzled]
    __shared__ __align__(16) bf16 PsT[4][32][64];   // per-wave P [qrow][key-swizzled]

    bf16x8 qf[2][2];  // [am][kc]  (B-operand: lane lm = q-row)
    #pragma unroll
    for (int am = 0; am < 2; am++)
        #pragma unroll
        for (int kc = 0; kc < 2; kc++) {
            int r = q0 + wm + am * 16 + lm;
            qf[am][kc] = *(const bf16x8*)(base + (size_t)r * (3 * C_) + kc * 32 + quad * 8);
        }

    floatx4 acc_o[2][4];
    #pragma unroll
    for (int am = 0; am < 2; am++)
        #pragma unroll
        for (int dn = 0; dn < 4; dn++) { floatx4 z = {0.f, 0.f, 0.f, 0.f}; acc_o[am][dn] = z; }
    float mst[2] = { -1e30f, -1e30f };
    float lst[2] = { 0.0f, 0.0f };

    int scol = (tid & 7) * 8;

    int kmax = q0 + QT_;
    for (int k0 = 0; k0 < kmax; k0 += KT_) {
        int kr0 = tid >> 3;               // 0..31
        bf16x8 kv0 = *(const bf16x8*)(base + (size_t)(k0 + kr0)      * (3 * C_) + HD_ + scol);
        bf16x8 kv1 = *(const bf16x8*)(base + (size_t)(k0 + kr0 + 32) * (3 * C_) + HD_ + scol);
        bf16x8 vv0 = *(const bf16x8*)(base + (size_t)(k0 + kr0)      * (3 * C_) + 2 * HD_ + scol);
        bf16x8 vv1 = *(const bf16x8*)(base + (size_t)(k0 + kr0 + 32) * (3 * C_) + 2 * HD_ + scol);
        __syncthreads();
        *(bf16x8*)(&Ks[kr0][scol])      = kv0;
        *(bf16x8*)(&Ks[kr0 + 32][scol]) = kv1;
        {
            int c = scol >> 3;
            int pk0 = (((kr0)       >> 3) ^ c) * 8 + (kr0 & 7);
            int pk1 = (((kr0 + 32)  >> 3) ^ c) * 8 + (kr0 & 7);
            #pragma unroll
            for (int j = 0; j < 8; j++) {
                Vt[scol + j][pk0] = vv0[j];
                Vt[scol + j][pk1] = vv1[j];
            }
        }
        __syncthreads();

        if (k0 <= q0 + wm + 31) {
            floatx4 st[4][2];
            #pragma unroll
            for (int bn = 0; bn < 4; bn++)
                #pragma unroll
                for (int am = 0; am < 2; am++) { floatx4 z = {0.f, 0.f, 0.f, 0.f}; st[bn][am] = z; }
            #pragma unroll
            for (int kc = 0; kc < 2; kc++) {
                bf16x8 kf[4];
                #pragma unroll
                for (int bn = 0; bn < 4; bn++)
                    kf[bn] = *(const bf16x8*)(&Ks[bn * 16 + lm][kc * 32 + quad * 8]);
                #pragma unroll
                for (int bn = 0; bn < 4; bn++)
                    #pragma unroll
                    for (int am = 0; am < 2; am++)
                        st[bn][am] = __builtin_amdgcn_mfma_f32_16x16x32_bf16(kf[bn], qf[am][kc], st[bn][am], 0, 0, 0);
            }

            float alpha_s[2];
            #pragma unroll
            for (int am = 0; am < 2; am++) {
                int gq = q0 + wm + am * 16 + lm;           // this lane's q-row
                int need_mask = (k0 + KT_ - 1) > (q0 + wm + am * 16);
                float vv[4][4];
                float rm = -1e30f;
                #pragma unroll
                for (int bn = 0; bn < 4; bn++)
                    #pragma unroll
                    for (int r = 0; r < 4; r++) {
                        float sv = st[bn][am][r] * 0.125f;  // 1/sqrt(64)
                        int key = k0 + bn * 16 + quad * 4 + r;
                        sv = (!need_mask || key <= gq) ? sv : -1e30f;
                        vv[bn][r] = sv;
                        rm = fmaxf(rm, sv);
                    }
                rm = fmaxf(rm, __shfl_xor(rm, 16));
                rm = fmaxf(rm, __shfl_xor(rm, 32));
                float mold = mst[am];
                float mnew = fmaxf(mold, rm);
                float alpha = __expf(mold - mnew);
                mst[am] = mnew;
                float ps = 0.f;
                #pragma unroll
                for (int bn = 0; bn < 4; bn++) {
                    float p0 = __expf(vv[bn][0] - mnew);
                    float p1 = __expf(vv[bn][1] - mnew);
                    float p2 = __expf(vv[bn][2] - mnew);
                    float p3 = __expf(vv[bn][3] - mnew);
                    ps += (p0 + p1) + (p2 + p3);
                    bf16x4 pk = { (bf16)p0, (bf16)p1, (bf16)p2, (bf16)p3 };
                    int kb = bn * 2 + (quad >> 1);
                    int col = ((kb ^ sw) << 3) + (quad & 1) * 4;
                    *(bf16x4*)(&PsT[wid][am * 16 + lm][col]) = pk;
                }
                ps += __shfl_xor(ps, 16);
                ps += __shfl_xor(ps, 32);
                lst[am] = lst[am] * alpha + ps;
                alpha_s[am] = alpha;
            }

            #pragma unroll
            for (int am = 0; am < 2; am++)
                #pragma unroll
                for (int r = 0; r < 4; r++) {
                    float ar = __shfl(alpha_s[am], quad * 4 + r);
                    #pragma unroll
                    for (int dn = 0; dn < 4; dn++) acc_o[am][dn][r] *= ar;
                }

            __asm__ volatile("s_waitcnt lgkmcnt(0)" ::: "memory");

            #pragma unroll
            for (int kc = 0; kc < 2; kc++) {
                bf16x8 pa[2], vfr[4];
                #pragma unroll
                for (int am = 0; am < 2; am++)
                    pa[am] = *(const bf16x8*)(&PsT[wid][am * 16 + lm][((kc * 4 + quad) ^ sw) << 3]);
                #pragma unroll
                for (int dn = 0; dn < 4; dn++) {
                    int d = dn * 16 + lm;
                    int swd = (d >> 3) & 7;
                    vfr[dn] = *(const bf16x8*)(&Vt[d][(((kc * 4 + quad) ^ swd) << 3)]);
                }
                #pragma unroll
                for (int am = 0; am < 2; am++)
                    #pragma unroll
                    for (int dn = 0; dn < 4; dn++)
                        acc_o[am][dn] = __builtin_amdgcn_mfma_f32_16x16x32_bf16(pa[am], vfr[dn], acc_o[am][dn], 0, 0, 0);
            }
        }
    }

    #pragma unroll
    for (int am = 0; am < 2; am++) {
        float il = 1.0f / lst[am];
        #pragma unroll
        for (int r = 0; r < 4; r++) {
            float ir = __shfl(il, quad * 4 + r);
            int qrow = q0 + wm + am * 16 + quad * 4 + r;
            bf16* orow = o + ((size_t)b * T_ + qrow) * C_ + h * HD_;
            #pragma unroll
            for (int dn = 0; dn < 4; dn++)
                orow[dn * 16 + lm] = (bf16)(acc_o[am][dn][r] * ir);
        }
    }
}

// ---------------------------------------------------------------------------
extern "C" void kernel_launch(void* const* d_in, const int* in_sizes, int n_in,
                              void* d_out, int out_size, void* d_ws, size_t ws_size,
                              hipStream_t stream) {
    (void)in_sizes; (void)n_in; (void)out_size; (void)ws_size;
    const float* x      = (const float*)d_in[0];
    const float* ln1_g  = (const float*)d_in[1];
    const float* ln1_b  = (const float*)d_in[2];
    const float* ln2_g  = (const float*)d_in[3];
    const float* ln2_b  = (const float*)d_in[4];
    const float* w_in   = (const float*)d_in[5];
    const float* b_in   = (const float*)d_in[6];
    const float* w_out  = (const float*)d_in[7];
    const float* b_out  = (const float*)d_in[8];
    const float* w_fc   = (const float*)d_in[9];
    const float* b_fc   = (const float*)d_in[10];
    const float* w_proj = (const float*)d_in[11];
    const float* b_proj = (const float*)d_in[12];

    char* ws = (char*)d_ws;
    const size_t MB = 1024 * 1024;
    bf16*  w_inT   = (bf16*)(ws + 0);        // 6 MB
    bf16*  w_outT  = (bf16*)(ws + 6 * MB);   // 2 MB
    bf16*  w_fcT   = (bf16*)(ws + 8 * MB);   // 8 MB
    bf16*  w_projT = (bf16*)(ws + 16 * MB);  // 8 MB
    bf16*  qkv     = (bf16*)(ws + 24 * MB);  // 24 MB (shares 32MB region with fc_act)
    bf16*  fc_act  = (bf16*)(ws + 24 * MB);  // 32 MB
    bf16*  o_buf   = (bf16*)(ws + 56 * MB);  // 8 MB (shares with y_b)
    bf16*  y_b     = (bf16*)(ws + 56 * MB);  // 8 MB
    bf16*  h_b     = (bf16*)(ws + 64 * MB);  // 8 MB (shares 16MB region with x1)
    float* x1      = (float*)(ws + 64 * MB); // 16 MB
    float* y_f     = (float*)(ws + 80 * MB); // 16 MB

    const int M = B_ * T_;  // 4096

    transpose_all<<<12288, dim3(32, 8), 0, stream>>>(w_in, w_out, w_fc, w_proj,
                                                     w_inT, w_outT, w_fcT, w_projT);

    ln_kernel<<<M, 256, 0, stream>>>(x, ln1_g, ln1_b, h_b, nullptr);
    gemm128<128, 0><<<dim3(3 * C_ / 128, M / 128), 256, 0, stream>>>(h_b, w_inT, b_in, nullptr,
                                                                     qkv, M, 3 * C_, C_);
    attn_mfma_kernel<<<dim3(B_ * H_, T_ / QT_), 256, 0, stream>>>(qkv, o_buf);
    gemm_nrw<2><<<dim3((C_ / 64) * (M / 128)), 256, 0, stream>>>(o_buf, w_outT, b_out, x,
                                                                 x1, M, C_, C_);
    ln_kernel<<<M, 256, 0, stream>>>(x1, ln2_g, ln2_b, y_b, y_f);
    gemm128<128, 1><<<dim3(4 * C_ / 128, M / 128), 256, 0, stream>>>(y_b, w_fcT, b_fc, nullptr,
                                                                     fc_act, M, 4 * C_, C_);
    gemm_nrw<2><<<dim3((C_ / 64) * (M / 128)), 256, 0, stream>>>(fc_act, w_projT, b_proj, y_f,
                                                                 (float*)d_out, M, C_, 4 * C_);
}

// Round 7
// 373.919 us; speedup vs baseline: 1.1606x; 1.0459x over previous
//
#include <hip/hip_runtime.h>
#include <hip/hip_bf16.h>
#include <math.h>

typedef __bf16 bf16;
typedef __bf16 bf16x8 __attribute__((ext_vector_type(8)));
typedef __bf16 bf16x4 __attribute__((ext_vector_type(4)));
typedef float floatx4 __attribute__((ext_vector_type(4)));

#define B_ 2
#define T_ 2048
#define C_ 1024
#define H_ 16
#define HD_ 64

// Fragment-order layout for a GEMM operand X[R][Kd] (both A and B sides):
//   tile (rt = r>>4, kc = k>>5), tile base = (rt*(Kd>>5)+kc)*512 elements,
//   within tile: lane = (r&15) + 16*((k>>3)&3), elem = k&7  -> lane*8+elem.
// One wave frag load = 64 lanes x 16B contiguous = 1KB, perfectly coalesced.

// async global->LDS, 16B per lane; lds dest = uniform base + lane*16
__device__ __forceinline__ void gload_lds16(const bf16* g, bf16* l) {
    __builtin_amdgcn_global_load_lds(
        (const __attribute__((address_space(1))) unsigned int*)(g),
        (__attribute__((address_space(3))) unsigned int*)(l), 16, 0, 0);
}

// ---------------------------------------------------------------------------
// All weight preprocessing in ONE launch.
//  blocks [0,3072):    w_in   fp32(K=1024,N=3072) -> bf16 row-major (N,K)
//  blocks [3072,7168): w_fc   fp32(1024,4096)     -> bf16 row-major (N,K)
//  blocks [7168,7680): w_out  fp32(1024,1024)     -> bf16 FRAG order (R=N,Kd=K)
//  blocks [7680,9728): w_proj fp32(4096,1024)     -> bf16 FRAG order
// ---------------------------------------------------------------------------
__global__ __launch_bounds__(256) void transpose_all(
        const float* __restrict__ w_in, const float* __restrict__ w_out,
        const float* __restrict__ w_fc, const float* __restrict__ w_proj,
        bf16* __restrict__ o_in, bf16* __restrict__ o_out,
        bf16* __restrict__ o_fc, bf16* __restrict__ o_proj) {
    __shared__ float shf[64 * 33];
    int t = blockIdx.x;
    int tid = threadIdx.x;
    if (t < 7168) {
        // row-major transpose path, 32x32 tiles
        const float* src; bf16* dst; int K, N, idx;
        if (t < 3072) { src = w_in; dst = o_in; K = 1024; N = 3072; idx = t; }
        else          { src = w_fc; dst = o_fc; K = 1024; N = 4096; idx = t - 3072; }
        int ntx = N >> 5;
        int nt = (idx % ntx) * 32, kt = (idx / ntx) * 32;
        int tx = tid & 31, ty = tid >> 5;  // 32 x 8
        #pragma unroll
        for (int i = 0; i < 32; i += 8)
            shf[(ty + i) * 33 + tx] = src[(size_t)(kt + ty + i) * N + nt + tx];
        __syncthreads();
        #pragma unroll
        for (int i = 0; i < 32; i += 8)
            dst[(size_t)(nt + ty + i) * K + kt + tx] = (bf16)shf[tx * 33 + ty + i];
    } else {
        // frag-order path: block handles 32 n x 64 k -> 4 frag tiles
        const float* src; bf16* dst; int K, idx;
        if (t < 7680) { src = w_out;  dst = o_out;  K = 1024; idx = t - 7168; }
        else          { src = w_proj; dst = o_proj; K = 4096; idx = t - 7680; }
        const int N = 1024;
        int n0 = (idx & 31) * 32, k0 = (idx >> 5) * 64;
        int col = tid & 31, kr = tid >> 5;
        #pragma unroll
        for (int s = 0; s < 8; s++)
            shf[(kr + s * 8) * 33 + col] = src[(size_t)(k0 + kr + s * 8) * N + n0 + col];
        __syncthreads();
        int tl = tid >> 6, l = tid & 63;
        int ntl = tl & 1, kcl = tl >> 1;
        int rr = ntl * 16 + (l & 15);
        int qd = l >> 4;
        bf16x8 v;
        #pragma unroll
        for (int e = 0; e < 8; e++)
            v[e] = (bf16)shf[(kcl * 32 + qd * 8 + e) * 33 + rr];
        size_t nt_g = (n0 >> 4) + ntl, kc_g = (k0 >> 5) + kcl;
        *(bf16x8*)(dst + (nt_g * (K >> 5) + kc_g) * 512 + l * 8) = v;
    }
}

// ---------------------------------------------------------------------------
// LayerNorm over C=1024. One block (256 threads) per row; 4 floats/thread.
// ---------------------------------------------------------------------------
__global__ __launch_bounds__(256) void ln_kernel(const float* __restrict__ x,
                                                 const float* __restrict__ g,
                                                 const float* __restrict__ b,
                                                 bf16* __restrict__ out_b,
                                                 float* __restrict__ out_f) {
    int row = blockIdx.x;
    int tid = threadIdx.x;
    const float* xr = x + (size_t)row * C_;
    float4 v = ((const float4*)xr)[tid];
    float s  = v.x + v.y + v.z + v.w;
    float ss = v.x * v.x + v.y * v.y + v.z * v.z + v.w * v.w;
    #pragma unroll
    for (int off = 32; off; off >>= 1) {
        s  += __shfl_down(s, off);
        ss += __shfl_down(ss, off);
    }
    __shared__ float red[8];
    int wid = tid >> 6;
    if ((tid & 63) == 0) { red[wid] = s; red[wid + 4] = ss; }
    __syncthreads();
    s  = red[0] + red[1] + red[2] + red[3];
    ss = red[4] + red[5] + red[6] + red[7];
    float mean = s * (1.0f / C_);
    float var  = ss * (1.0f / C_) - mean * mean;
    float rstd = rsqrtf(var + 1e-5f);
    float4 gv = ((const float4*)g)[tid];
    float4 bv = ((const float4*)b)[tid];
    float o0 = (v.x - mean) * rstd * gv.x + bv.x;
    float o1 = (v.y - mean) * rstd * gv.y + bv.y;
    float o2 = (v.z - mean) * rstd * gv.z + bv.z;
    float o3 = (v.w - mean) * rstd * gv.w + bv.w;
    bf16x4 ob = { (bf16)o0, (bf16)o1, (bf16)o2, (bf16)o3 };
    ((bf16x4*)out_b)[(size_t)row * 256 + tid] = ob;
    if (out_f) {
        float4 of; of.x = o0; of.y = o1; of.z = o2; of.w = o3;
        ((float4*)out_f)[(size_t)row * 256 + tid] = of;
    }
}

// ---------------------------------------------------------------------------
// m97-structure wide GEMM: C = A @ Bt^T, 128x128 tile, 256 thr = 4 waves.
// MODE 0: +bias, bf16 row-major out (qkv).
// MODE 1: +bias+gelu, bf16 FRAG-ORDER out via padded-LDS roundtrip (fc_act).
// ---------------------------------------------------------------------------
__device__ __forceinline__ float gelu_exact(float v) {
    return 0.5f * v * (1.0f + erff(v * 0.70710678118654752f));
}

template<int MODE>
__global__ __launch_bounds__(256) void gemm128(const bf16* __restrict__ A,
                                               const bf16* __restrict__ Bt,
                                               const float* __restrict__ bias,
                                               void* __restrict__ out,
                                               int M, int N, int K) {
    __shared__ __align__(16) bf16 smem[128 * 136];   // staging 32KB; MODE1 epilogue stage 128x136
    bf16* As = smem;
    bf16* Bs = smem + 128 * 64;

    int m0 = blockIdx.y * 128, n0 = blockIdx.x * 128;
    int tid = threadIdx.x;
    int wid = __builtin_amdgcn_readfirstlane(tid >> 6);
    int lane = tid & 63;
    int lm = lane & 15, quad = lane >> 4;
    int wm = (wid & 1) * 64;
    int wn = (wid >> 1) * 64;
    int lrow = lane >> 3;
    int lcol = (lane & 7) * 8;

    const bf16* Ablk = A  + (size_t)m0 * K;
    const bf16* Bblk = Bt + (size_t)n0 * K;

    floatx4 acc[4][4];
    #pragma unroll
    for (int i = 0; i < 4; i++)
        #pragma unroll
        for (int j = 0; j < 4; j++) { floatx4 z = {0.f, 0.f, 0.f, 0.f}; acc[i][j] = z; }

    for (int k0 = 0; k0 < K; k0 += 64) {
        __syncthreads();
        #pragma unroll
        for (int c = 0; c < 4; c++) {
            int row = wid * 32 + c * 8;
            gload_lds16(Ablk + (size_t)(row + lrow) * K + k0 + lcol, As + row * 64);
        }
        #pragma unroll
        for (int c = 0; c < 4; c++) {
            int row = wid * 32 + c * 8;
            gload_lds16(Bblk + (size_t)(row + lrow) * K + k0 + lcol, Bs + row * 64);
        }
        __syncthreads();
        #pragma unroll
        for (int kc = 0; kc < 2; kc++) {
            bf16x8 af[4], bfr[4];
            #pragma unroll
            for (int i = 0; i < 4; i++)
                af[i] = *(const bf16x8*)(As + (wm + i * 16 + lm) * 64 + kc * 32 + quad * 8);
            #pragma unroll
            for (int j = 0; j < 4; j++)
                bfr[j] = *(const bf16x8*)(Bs + (wn + j * 16 + lm) * 64 + kc * 32 + quad * 8);
            #pragma unroll
            for (int i = 0; i < 4; i++)
                #pragma unroll
                for (int j = 0; j < 4; j++)
                    acc[i][j] = __builtin_amdgcn_mfma_f32_16x16x32_bf16(af[i], bfr[j], acc[i][j], 0, 0, 0);
        }
    }

    if (MODE == 0) {
        #pragma unroll
        for (int i = 0; i < 4; i++)
            #pragma unroll
            for (int j = 0; j < 4; j++) {
                int mbase = m0 + wm + i * 16 + quad * 4;
                int n     = n0 + wn + j * 16 + lm;
                float bsn = bias[n];
                #pragma unroll
                for (int r = 0; r < 4; r++)
                    ((bf16*)out)[(size_t)(mbase + r) * N + n] = (bf16)(acc[i][j][r] + bsn);
            }
    } else {
        // stage gelu(C) into padded LDS, then frag-order coalesced stores
        __syncthreads();
        #pragma unroll
        for (int i = 0; i < 4; i++)
            #pragma unroll
            for (int j = 0; j < 4; j++) {
                int n = n0 + wn + j * 16 + lm;
                float bsn = bias[n];
                #pragma unroll
                for (int r = 0; r < 4; r++)
                    smem[(wm + i * 16 + quad * 4 + r) * 136 + wn + j * 16 + lm] =
                        (bf16)gelu_exact(acc[i][j][r] + bsn);
            }
        __syncthreads();
        bf16* ob = (bf16*)out;
        int kcb = n0 >> 5;
        #pragma unroll
        for (int p = 0; p < 8; p++) {
            int tl = wid * 8 + p;
            int mtl = tl >> 2, kcl = tl & 3;
            bf16x8 v = *(const bf16x8*)&smem[(mtl * 16 + lm) * 136 + kcl * 32 + quad * 8];
            *(bf16x8*)(ob + (((size_t)((m0 >> 4) + mtl) * (N >> 5) + kcb + kcl) * 512) + lane * 8) = v;
        }
    }
}

// ---------------------------------------------------------------------------
// Narrow-N GEMM, fully LDS-free: both operands in frag order, direct
// global->register loads (1KB coalesced per frag), register double-buffer
// across k-iterations, NO barriers. 128x64 block tile, 4 waves (64x32 each).
// 1D grid, XCD swizzle (requires M/128==32, N==1024).
// out f32 = acc + bias + add (row-major).
// ---------------------------------------------------------------------------
__global__ __launch_bounds__(256) void gemm_direct(const bf16* __restrict__ Af,
                                                   const bf16* __restrict__ Bf,
                                                   const float* __restrict__ bias,
                                                   const float* __restrict__ add,
                                                   float* __restrict__ out,
                                                   int M, int N, int K) {
    int lin = blockIdx.x;
    int xcd = lin & 7, loc = lin >> 3;
    int m0 = ((xcd << 2) | (loc & 3)) * 128;
    int n0 = (loc >> 2) * 64;
    int tid = threadIdx.x;
    int wid = __builtin_amdgcn_readfirstlane(tid >> 6);
    int lane = tid & 63;
    int lm = lane & 15, quad = lane >> 4;
    int wm = (wid & 1) * 64, wn = (wid >> 1) * 32;
    int KC = K >> 5;
    const bf16* Ab = Af + ((size_t)((m0 + wm) >> 4) * KC) * 512 + lane * 8;
    const bf16* Bb = Bf + ((size_t)((n0 + wn) >> 4) * KC) * 512 + lane * 8;

    floatx4 acc[4][2];
    #pragma unroll
    for (int i = 0; i < 4; i++)
        #pragma unroll
        for (int j = 0; j < 2; j++) { floatx4 z = {0.f, 0.f, 0.f, 0.f}; acc[i][j] = z; }

    bf16x8 ac[4][2], bc[2][2], an[4][2], bn[2][2];
    #pragma unroll
    for (int i = 0; i < 4; i++)
        #pragma unroll
        for (int c = 0; c < 2; c++)
            ac[i][c] = *(const bf16x8*)(Ab + ((size_t)i * KC + c) * 512);
    #pragma unroll
    for (int j = 0; j < 2; j++)
        #pragma unroll
        for (int c = 0; c < 2; c++)
            bc[j][c] = *(const bf16x8*)(Bb + ((size_t)j * KC + c) * 512);

    for (int kc0 = 0; kc0 < KC; kc0 += 2) {
        bool pre = (kc0 + 2) < KC;
        if (pre) {
            #pragma unroll
            for (int i = 0; i < 4; i++)
                #pragma unroll
                for (int c = 0; c < 2; c++)
                    an[i][c] = *(const bf16x8*)(Ab + ((size_t)i * KC + kc0 + 2 + c) * 512);
            #pragma unroll
            for (int j = 0; j < 2; j++)
                #pragma unroll
                for (int c = 0; c < 2; c++)
                    bn[j][c] = *(const bf16x8*)(Bb + ((size_t)j * KC + kc0 + 2 + c) * 512);
        }
        #pragma unroll
        for (int c = 0; c < 2; c++)
            #pragma unroll
            for (int i = 0; i < 4; i++)
                #pragma unroll
                for (int j = 0; j < 2; j++)
                    acc[i][j] = __builtin_amdgcn_mfma_f32_16x16x32_bf16(ac[i][c], bc[j][c], acc[i][j], 0, 0, 0);
        if (pre) {
            #pragma unroll
            for (int i = 0; i < 4; i++)
                #pragma unroll
                for (int c = 0; c < 2; c++) ac[i][c] = an[i][c];
            #pragma unroll
            for (int j = 0; j < 2; j++)
                #pragma unroll
                for (int c = 0; c < 2; c++) bc[j][c] = bn[j][c];
        }
    }

    #pragma unroll
    for (int i = 0; i < 4; i++)
        #pragma unroll
        for (int j = 0; j < 2; j++) {
            int mbase = m0 + wm + i * 16 + quad * 4;
            int n     = n0 + wn + j * 16 + lm;
            float bsn = bias[n];
            #pragma unroll
            for (int r = 0; r < 4; r++) {
                size_t idx = (size_t)(mbase + r) * N + n;
                out[idx] = acc[i][j][r] + bsn + add[idx];
            }
        }
}

// ---------------------------------------------------------------------------
// Flash attention, MFMA, S^T formulation. Output written in FRAG ORDER
// (A-operand layout for the attn-proj gemm_direct), via per-wave PsT roundtrip.
// ---------------------------------------------------------------------------
#define QT_ 128
#define KT_ 64

__global__ __launch_bounds__(256) void attn_mfma_kernel(const bf16* __restrict__ qkv,
                                                        bf16* __restrict__ of) {
    int bh = blockIdx.x;
    int b = bh >> 4, h = bh & 15;
    int q0 = (gridDim.y - 1 - blockIdx.y) * QT_;   // heavy-first
    int tid = threadIdx.x, wid = tid >> 6, lane = tid & 63;
    int wm = wid * 32;
    int lm = lane & 15, quad = lane >> 4;
    int sw = lm & 7;

    const bf16* base = qkv + (size_t)b * T_ * (3 * C_) + h * (3 * HD_);

    __shared__ __align__(16) bf16 Ks[KT_][72];      // K rows [key][d]
    __shared__ __align__(16) bf16 Vt[HD_][72];      // V^T [d][key-swizzled]
    __shared__ __align__(16) bf16 PsT[4][32][64];   // per-wave P [qrow][key-swizzled]

    bf16x8 qf[2][2];  // [am][kc]  (B-operand: lane lm = q-row)
    #pragma unroll
    for (int am = 0; am < 2; am++)
        #pragma unroll
        for (int kc = 0; kc < 2; kc++) {
            int r = q0 + wm + am * 16 + lm;
            qf[am][kc] = *(const bf16x8*)(base + (size_t)r * (3 * C_) + kc * 32 + quad * 8);
        }

    floatx4 acc_o[2][4];
    #pragma unroll
    for (int am = 0; am < 2; am++)
        #pragma unroll
        for (int dn = 0; dn < 4; dn++) { floatx4 z = {0.f, 0.f, 0.f, 0.f}; acc_o[am][dn] = z; }
    float mst[2] = { -1e30f, -1e30f };
    float lst[2] = { 0.0f, 0.0f };

    int scol = (tid & 7) * 8;

    int kmax = q0 + QT_;
    for (int k0 = 0; k0 < kmax; k0 += KT_) {
        int kr0 = tid >> 3;               // 0..31
        bf16x8 kv0 = *(const bf16x8*)(base + (size_t)(k0 + kr0)      * (3 * C_) + HD_ + scol);
        bf16x8 kv1 = *(const bf16x8*)(base + (size_t)(k0 + kr0 + 32) * (3 * C_) + HD_ + scol);
        bf16x8 vv0 = *(const bf16x8*)(base + (size_t)(k0 + kr0)      * (3 * C_) + 2 * HD_ + scol);
        bf16x8 vv1 = *(const bf16x8*)(base + (size_t)(k0 + kr0 + 32) * (3 * C_) + 2 * HD_ + scol);
        __syncthreads();
        *(bf16x8*)(&Ks[kr0][scol])      = kv0;
        *(bf16x8*)(&Ks[kr0 + 32][scol]) = kv1;
        {
            int c = scol >> 3;
            int pk0 = (((kr0)       >> 3) ^ c) * 8 + (kr0 & 7);
            int pk1 = (((kr0 + 32)  >> 3) ^ c) * 8 + (kr0 & 7);
            #pragma unroll
            for (int j = 0; j < 8; j++) {
                Vt[scol + j][pk0] = vv0[j];
                Vt[scol + j][pk1] = vv1[j];
            }
        }
        __syncthreads();

        if (k0 <= q0 + wm + 31) {
            floatx4 st[4][2];
            #pragma unroll
            for (int bn = 0; bn < 4; bn++)
                #pragma unroll
                for (int am = 0; am < 2; am++) { floatx4 z = {0.f, 0.f, 0.f, 0.f}; st[bn][am] = z; }
            #pragma unroll
            for (int kc = 0; kc < 2; kc++) {
                bf16x8 kf[4];
                #pragma unroll
                for (int bn = 0; bn < 4; bn++)
                    kf[bn] = *(const bf16x8*)(&Ks[bn * 16 + lm][kc * 32 + quad * 8]);
                #pragma unroll
                for (int bn = 0; bn < 4; bn++)
                    #pragma unroll
                    for (int am = 0; am < 2; am++)
                        st[bn][am] = __builtin_amdgcn_mfma_f32_16x16x32_bf16(kf[bn], qf[am][kc], st[bn][am], 0, 0, 0);
            }

            float alpha_s[2];
            #pragma unroll
            for (int am = 0; am < 2; am++) {
                int gq = q0 + wm + am * 16 + lm;           // this lane's q-row
                int need_mask = (k0 + KT_ - 1) > (q0 + wm + am * 16);
                float vv[4][4];
                float rm = -1e30f;
                #pragma unroll
                for (int bn = 0; bn < 4; bn++)
                    #pragma unroll
                    for (int r = 0; r < 4; r++) {
                        float sv = st[bn][am][r] * 0.125f;  // 1/sqrt(64)
                        int key = k0 + bn * 16 + quad * 4 + r;
                        sv = (!need_mask || key <= gq) ? sv : -1e30f;
                        vv[bn][r] = sv;
                        rm = fmaxf(rm, sv);
                    }
                rm = fmaxf(rm, __shfl_xor(rm, 16));
                rm = fmaxf(rm, __shfl_xor(rm, 32));
                float mold = mst[am];
                float mnew = fmaxf(mold, rm);
                float alpha = __expf(mold - mnew);
                mst[am] = mnew;
                float ps = 0.f;
                #pragma unroll
                for (int bn = 0; bn < 4; bn++) {
                    float p0 = __expf(vv[bn][0] - mnew);
                    float p1 = __expf(vv[bn][1] - mnew);
                    float p2 = __expf(vv[bn][2] - mnew);
                    float p3 = __expf(vv[bn][3] - mnew);
                    ps += (p0 + p1) + (p2 + p3);
                    bf16x4 pk = { (bf16)p0, (bf16)p1, (bf16)p2, (bf16)p3 };
                    int kb = bn * 2 + (quad >> 1);
                    int col = ((kb ^ sw) << 3) + (quad & 1) * 4;
                    *(bf16x4*)(&PsT[wid][am * 16 + lm][col]) = pk;
                }
                ps += __shfl_xor(ps, 16);
                ps += __shfl_xor(ps, 32);
                lst[am] = lst[am] * alpha + ps;
                alpha_s[am] = alpha;
            }

            #pragma unroll
            for (int am = 0; am < 2; am++)
                #pragma unroll
                for (int r = 0; r < 4; r++) {
                    float ar = __shfl(alpha_s[am], quad * 4 + r);
                    #pragma unroll
                    for (int dn = 0; dn < 4; dn++) acc_o[am][dn][r] *= ar;
                }

            __asm__ volatile("s_waitcnt lgkmcnt(0)" ::: "memory");

            #pragma unroll
            for (int kc = 0; kc < 2; kc++) {
                bf16x8 pa[2], vfr[4];
                #pragma unroll
                for (int am = 0; am < 2; am++)
                    pa[am] = *(const bf16x8*)(&PsT[wid][am * 16 + lm][((kc * 4 + quad) ^ sw) << 3]);
                #pragma unroll
                for (int dn = 0; dn < 4; dn++) {
                    int d = dn * 16 + lm;
                    int swd = (d >> 3) & 7;
                    vfr[dn] = *(const bf16x8*)(&Vt[d][(((kc * 4 + quad) ^ swd) << 3)]);
                }
                #pragma unroll
                for (int am = 0; am < 2; am++)
                    #pragma unroll
                    for (int dn = 0; dn < 4; dn++)
                        acc_o[am][dn] = __builtin_amdgcn_mfma_f32_16x16x32_bf16(pa[am], vfr[dn], acc_o[am][dn], 0, 0, 0);
            }
        }
    }

    // epilogue: normalize, stage C->A-frag via per-wave PsT, frag-order store
    #pragma unroll
    for (int am = 0; am < 2; am++) {
        float il = 1.0f / lst[am];
        #pragma unroll
        for (int r = 0; r < 4; r++) {
            float ir = __shfl(il, quad * 4 + r);
            #pragma unroll
            for (int dn = 0; dn < 4; dn++)
                PsT[wid][am * 16 + quad * 4 + r][dn * 16 + lm] = (bf16)(acc_o[am][dn][r] * ir);
        }
    }
    __asm__ volatile("s_waitcnt lgkmcnt(0)" ::: "memory");
    size_t mtb = ((size_t)b * T_ + q0 + wm) >> 4;
    #pragma unroll
    for (int am = 0; am < 2; am++)
        #pragma unroll
        for (int kcl = 0; kcl < 2; kcl++) {
            bf16x8 v = *(const bf16x8*)&PsT[wid][am * 16 + lm][kcl * 32 + quad * 8];
            *(bf16x8*)(of + ((mtb + am) * (C_ >> 5) + (h * 2 + kcl)) * 512 + lane * 8) = v;
        }
}

// ---------------------------------------------------------------------------
extern "C" void kernel_launch(void* const* d_in, const int* in_sizes, int n_in,
                              void* d_out, int out_size, void* d_ws, size_t ws_size,
                              hipStream_t stream) {
    (void)in_sizes; (void)n_in; (void)out_size; (void)ws_size;
    const float* x      = (const float*)d_in[0];
    const float* ln1_g  = (const float*)d_in[1];
    const float* ln1_b  = (const float*)d_in[2];
    const float* ln2_g  = (const float*)d_in[3];
    const float* ln2_b  = (const float*)d_in[4];
    const float* w_in   = (const float*)d_in[5];
    const float* b_in   = (const float*)d_in[6];
    const float* w_out  = (const float*)d_in[7];
    const float* b_out  = (const float*)d_in[8];
    const float* w_fc   = (const float*)d_in[9];
    const float* b_fc   = (const float*)d_in[10];
    const float* w_proj = (const float*)d_in[11];
    const float* b_proj = (const float*)d_in[12];

    char* ws = (char*)d_ws;
    const size_t MB = 1024 * 1024;
    bf16*  w_inT   = (bf16*)(ws + 0);        // 6 MB row-major (N,K)
    bf16*  w_outF  = (bf16*)(ws + 6 * MB);   // 2 MB frag
    bf16*  w_fcT   = (bf16*)(ws + 8 * MB);   // 8 MB row-major (N,K)
    bf16*  w_projF = (bf16*)(ws + 16 * MB);  // 8 MB frag
    bf16*  qkv     = (bf16*)(ws + 24 * MB);  // 24 MB (shares 32MB region with fc_frag)
    bf16*  fc_frag = (bf16*)(ws + 24 * MB);  // 32 MB frag
    bf16*  o_frag  = (bf16*)(ws + 56 * MB);  // 8 MB frag (shares with y_b)
    bf16*  y_b     = (bf16*)(ws + 56 * MB);  // 8 MB
    bf16*  h_b     = (bf16*)(ws + 64 * MB);  // 8 MB (shares 16MB region with x1)
    float* x1      = (float*)(ws + 64 * MB); // 16 MB
    float* y_f     = (float*)(ws + 80 * MB); // 16 MB

    const int M = B_ * T_;  // 4096

    transpose_all<<<9728, 256, 0, stream>>>(w_in, w_out, w_fc, w_proj,
                                            w_inT, w_outF, w_fcT, w_projF);

    ln_kernel<<<M, 256, 0, stream>>>(x, ln1_g, ln1_b, h_b, nullptr);
    gemm128<0><<<dim3(3 * C_ / 128, M / 128), 256, 0, stream>>>(h_b, w_inT, b_in,
                                                                qkv, M, 3 * C_, C_);
    attn_mfma_kernel<<<dim3(B_ * H_, T_ / QT_), 256, 0, stream>>>(qkv, o_frag);
    gemm_direct<<<512, 256, 0, stream>>>(o_frag, w_outF, b_out, x, x1, M, C_, C_);
    ln_kernel<<<M, 256, 0, stream>>>(x1, ln2_g, ln2_b, y_b, y_f);
    gemm128<1><<<dim3(4 * C_ / 128, M / 128), 256, 0, stream>>>(y_b, w_fcT, b_fc,
                                                                fc_frag, M, 4 * C_, C_);
    gemm_direct<<<512, 256, 0, stream>>>(fc_frag, w_projF, b_proj, y_f,
                                         (float*)d_out, M, C_, 4 * C_);
}

// Round 8
// 354.429 us; speedup vs baseline: 1.2244x; 1.0550x over previous
//
#include <hip/hip_runtime.h>
#include <hip/hip_bf16.h>
#include <math.h>

typedef __bf16 bf16;
typedef __bf16 bf16x8 __attribute__((ext_vector_type(8)));
typedef __bf16 bf16x4 __attribute__((ext_vector_type(4)));
typedef float floatx4 __attribute__((ext_vector_type(4)));

#define B_ 2
#define T_ 2048
#define C_ 1024
#define H_ 16
#define HD_ 64

// Fragment-order layout for a GEMM operand X[R][Kd] (both A and B sides):
//   tile (rt = r>>4, kc = k>>5), tile base = (rt*(Kd>>5)+kc)*512 elements,
//   within tile: lane = (r&15) + 16*((k>>3)&3), elem = k&7  -> lane*8+elem.
// One wave frag load = 64 lanes x 16B contiguous = 1KB, perfectly coalesced.

// async global->LDS, 16B per lane; lds dest = uniform base + lane*16
__device__ __forceinline__ void gload_lds16(const bf16* g, bf16* l) {
    __builtin_amdgcn_global_load_lds(
        (const __attribute__((address_space(1))) unsigned int*)(g),
        (__attribute__((address_space(3))) unsigned int*)(l), 16, 0, 0);
}

// ---------------------------------------------------------------------------
// All weight preprocessing in ONE launch.
//  blocks [0,3072):    w_in   fp32(K=1024,N=3072) -> bf16 row-major (N,K)
//  blocks [3072,7168): w_fc   fp32(1024,4096)     -> bf16 row-major (N,K)
//  blocks [7168,7680): w_out  fp32(1024,1024)     -> bf16 FRAG order (R=N,Kd=K)
//  blocks [7680,9728): w_proj fp32(4096,1024)     -> bf16 FRAG order
// ---------------------------------------------------------------------------
__global__ __launch_bounds__(256) void transpose_all(
        const float* __restrict__ w_in, const float* __restrict__ w_out,
        const float* __restrict__ w_fc, const float* __restrict__ w_proj,
        bf16* __restrict__ o_in, bf16* __restrict__ o_out,
        bf16* __restrict__ o_fc, bf16* __restrict__ o_proj) {
    __shared__ float shf[64 * 33];
    int t = blockIdx.x;
    int tid = threadIdx.x;
    if (t < 7168) {
        const float* src; bf16* dst; int K, N, idx;
        if (t < 3072) { src = w_in; dst = o_in; K = 1024; N = 3072; idx = t; }
        else          { src = w_fc; dst = o_fc; K = 1024; N = 4096; idx = t - 3072; }
        int ntx = N >> 5;
        int nt = (idx % ntx) * 32, kt = (idx / ntx) * 32;
        int tx = tid & 31, ty = tid >> 5;  // 32 x 8
        #pragma unroll
        for (int i = 0; i < 32; i += 8)
            shf[(ty + i) * 33 + tx] = src[(size_t)(kt + ty + i) * N + nt + tx];
        __syncthreads();
        #pragma unroll
        for (int i = 0; i < 32; i += 8)
            dst[(size_t)(nt + ty + i) * K + kt + tx] = (bf16)shf[tx * 33 + ty + i];
    } else {
        const float* src; bf16* dst; int K, idx;
        if (t < 7680) { src = w_out;  dst = o_out;  K = 1024; idx = t - 7168; }
        else          { src = w_proj; dst = o_proj; K = 4096; idx = t - 7680; }
        const int N = 1024;
        int n0 = (idx & 31) * 32, k0 = (idx >> 5) * 64;
        int col = tid & 31, kr = tid >> 5;
        #pragma unroll
        for (int s = 0; s < 8; s++)
            shf[(kr + s * 8) * 33 + col] = src[(size_t)(k0 + kr + s * 8) * N + n0 + col];
        __syncthreads();
        int tl = tid >> 6, l = tid & 63;
        int ntl = tl & 1, kcl = tl >> 1;
        int rr = ntl * 16 + (l & 15);
        int qd = l >> 4;
        bf16x8 v;
        #pragma unroll
        for (int e = 0; e < 8; e++)
            v[e] = (bf16)shf[(kcl * 32 + qd * 8 + e) * 33 + rr];
        size_t nt_g = (n0 >> 4) + ntl, kc_g = (k0 >> 5) + kcl;
        *(bf16x8*)(dst + (nt_g * (K >> 5) + kc_g) * 512 + l * 8) = v;
    }
}

// ---------------------------------------------------------------------------
// LayerNorm over C=1024. One block (256 threads) per row; 4 floats/thread.
// ---------------------------------------------------------------------------
__global__ __launch_bounds__(256) void ln_kernel(const float* __restrict__ x,
                                                 const float* __restrict__ g,
                                                 const float* __restrict__ b,
                                                 bf16* __restrict__ out_b,
                                                 float* __restrict__ out_f) {
    int row = blockIdx.x;
    int tid = threadIdx.x;
    const float* xr = x + (size_t)row * C_;
    float4 v = ((const float4*)xr)[tid];
    float s  = v.x + v.y + v.z + v.w;
    float ss = v.x * v.x + v.y * v.y + v.z * v.z + v.w * v.w;
    #pragma unroll
    for (int off = 32; off; off >>= 1) {
        s  += __shfl_down(s, off);
        ss += __shfl_down(ss, off);
    }
    __shared__ float red[8];
    int wid = tid >> 6;
    if ((tid & 63) == 0) { red[wid] = s; red[wid + 4] = ss; }
    __syncthreads();
    s  = red[0] + red[1] + red[2] + red[3];
    ss = red[4] + red[5] + red[6] + red[7];
    float mean = s * (1.0f / C_);
    float var  = ss * (1.0f / C_) - mean * mean;
    float rstd = rsqrtf(var + 1e-5f);
    float4 gv = ((const float4*)g)[tid];
    float4 bv = ((const float4*)b)[tid];
    float o0 = (v.x - mean) * rstd * gv.x + bv.x;
    float o1 = (v.y - mean) * rstd * gv.y + bv.y;
    float o2 = (v.z - mean) * rstd * gv.z + bv.z;
    float o3 = (v.w - mean) * rstd * gv.w + bv.w;
    bf16x4 ob = { (bf16)o0, (bf16)o1, (bf16)o2, (bf16)o3 };
    ((bf16x4*)out_b)[(size_t)row * 256 + tid] = ob;
    if (out_f) {
        float4 of; of.x = o0; of.y = o1; of.z = o2; of.w = o3;
        ((float4*)out_f)[(size_t)row * 256 + tid] = of;
    }
}

// ---------------------------------------------------------------------------
// m97-structure wide GEMM: C = A @ Bt^T, 128x128 tile, 256 thr = 4 waves.
// MODE 0: +bias, bf16 row-major out (qkv).
// MODE 1: +bias+gelu, bf16 FRAG-ORDER out via padded-LDS roundtrip (fc_act).
// ---------------------------------------------------------------------------
__device__ __forceinline__ float gelu_exact(float v) {
    return 0.5f * v * (1.0f + erff(v * 0.70710678118654752f));
}

template<int MODE>
__global__ __launch_bounds__(256) void gemm128(const bf16* __restrict__ A,
                                               const bf16* __restrict__ Bt,
                                               const float* __restrict__ bias,
                                               void* __restrict__ out,
                                               int M, int N, int K) {
    __shared__ __align__(16) bf16 smem[128 * 136];
    bf16* As = smem;
    bf16* Bs = smem + 128 * 64;

    int m0 = blockIdx.y * 128, n0 = blockIdx.x * 128;
    int tid = threadIdx.x;
    int wid = __builtin_amdgcn_readfirstlane(tid >> 6);
    int lane = tid & 63;
    int lm = lane & 15, quad = lane >> 4;
    int wm = (wid & 1) * 64;
    int wn = (wid >> 1) * 64;
    int lrow = lane >> 3;
    int lcol = (lane & 7) * 8;

    const bf16* Ablk = A  + (size_t)m0 * K;
    const bf16* Bblk = Bt + (size_t)n0 * K;

    floatx4 acc[4][4];
    #pragma unroll
    for (int i = 0; i < 4; i++)
        #pragma unroll
        for (int j = 0; j < 4; j++) { floatx4 z = {0.f, 0.f, 0.f, 0.f}; acc[i][j] = z; }

    for (int k0 = 0; k0 < K; k0 += 64) {
        __syncthreads();
        #pragma unroll
        for (int c = 0; c < 4; c++) {
            int row = wid * 32 + c * 8;
            gload_lds16(Ablk + (size_t)(row + lrow) * K + k0 + lcol, As + row * 64);
        }
        #pragma unroll
        for (int c = 0; c < 4; c++) {
            int row = wid * 32 + c * 8;
            gload_lds16(Bblk + (size_t)(row + lrow) * K + k0 + lcol, Bs + row * 64);
        }
        __syncthreads();
        #pragma unroll
        for (int kc = 0; kc < 2; kc++) {
            bf16x8 af[4], bfr[4];
            #pragma unroll
            for (int i = 0; i < 4; i++)
                af[i] = *(const bf16x8*)(As + (wm + i * 16 + lm) * 64 + kc * 32 + quad * 8);
            #pragma unroll
            for (int j = 0; j < 4; j++)
                bfr[j] = *(const bf16x8*)(Bs + (wn + j * 16 + lm) * 64 + kc * 32 + quad * 8);
            #pragma unroll
            for (int i = 0; i < 4; i++)
                #pragma unroll
                for (int j = 0; j < 4; j++)
                    acc[i][j] = __builtin_amdgcn_mfma_f32_16x16x32_bf16(af[i], bfr[j], acc[i][j], 0, 0, 0);
        }
    }

    if (MODE == 0) {
        #pragma unroll
        for (int i = 0; i < 4; i++)
            #pragma unroll
            for (int j = 0; j < 4; j++) {
                int mbase = m0 + wm + i * 16 + quad * 4;
                int n     = n0 + wn + j * 16 + lm;
                float bsn = bias[n];
                #pragma unroll
                for (int r = 0; r < 4; r++)
                    ((bf16*)out)[(size_t)(mbase + r) * N + n] = (bf16)(acc[i][j][r] + bsn);
            }
    } else {
        __syncthreads();
        #pragma unroll
        for (int i = 0; i < 4; i++)
            #pragma unroll
            for (int j = 0; j < 4; j++) {
                int n = n0 + wn + j * 16 + lm;
                float bsn = bias[n];
                #pragma unroll
                for (int r = 0; r < 4; r++)
                    smem[(wm + i * 16 + quad * 4 + r) * 136 + wn + j * 16 + lm] =
                        (bf16)gelu_exact(acc[i][j][r] + bsn);
            }
        __syncthreads();
        bf16* ob = (bf16*)out;
        int kcb = n0 >> 5;
        #pragma unroll
        for (int p = 0; p < 8; p++) {
            int tl = wid * 8 + p;
            int mtl = tl >> 2, kcl = tl & 3;
            bf16x8 v = *(const bf16x8*)&smem[(mtl * 16 + lm) * 136 + kcl * 32 + quad * 8];
            *(bf16x8*)(ob + (((size_t)((m0 >> 4) + mtl) * (N >> 5) + kcb + kcl) * 512) + lane * 8) = v;
        }
    }
}

// ---------------------------------------------------------------------------
// Narrow-N GEMM, fully LDS-free: both operands in frag order, direct
// global->register loads, register double-buffer, NO barriers.
// 128x64 block tile, 4 waves (64x32 each). XCD-swizzled 1D grid.
// ---------------------------------------------------------------------------
__global__ __launch_bounds__(256) void gemm_direct(const bf16* __restrict__ Af,
                                                   const bf16* __restrict__ Bf,
                                                   const float* __restrict__ bias,
                                                   const float* __restrict__ add,
                                                   float* __restrict__ out,
                                                   int M, int N, int K) {
    int lin = blockIdx.x;
    int xcd = lin & 7, loc = lin >> 3;
    int m0 = ((xcd << 2) | (loc & 3)) * 128;
    int n0 = (loc >> 2) * 64;
    int tid = threadIdx.x;
    int wid = __builtin_amdgcn_readfirstlane(tid >> 6);
    int lane = tid & 63;
    int lm = lane & 15, quad = lane >> 4;
    int wm = (wid & 1) * 64, wn = (wid >> 1) * 32;
    int KC = K >> 5;
    const bf16* Ab = Af + ((size_t)((m0 + wm) >> 4) * KC) * 512 + lane * 8;
    const bf16* Bb = Bf + ((size_t)((n0 + wn) >> 4) * KC) * 512 + lane * 8;

    floatx4 acc[4][2];
    #pragma unroll
    for (int i = 0; i < 4; i++)
        #pragma unroll
        for (int j = 0; j < 2; j++) { floatx4 z = {0.f, 0.f, 0.f, 0.f}; acc[i][j] = z; }

    bf16x8 ac[4][2], bc[2][2], an[4][2], bn[2][2];
    #pragma unroll
    for (int i = 0; i < 4; i++)
        #pragma unroll
        for (int c = 0; c < 2; c++)
            ac[i][c] = *(const bf16x8*)(Ab + ((size_t)i * KC + c) * 512);
    #pragma unroll
    for (int j = 0; j < 2; j++)
        #pragma unroll
        for (int c = 0; c < 2; c++)
            bc[j][c] = *(const bf16x8*)(Bb + ((size_t)j * KC + c) * 512);

    for (int kc0 = 0; kc0 < KC; kc0 += 2) {
        bool pre = (kc0 + 2) < KC;
        if (pre) {
            #pragma unroll
            for (int i = 0; i < 4; i++)
                #pragma unroll
                for (int c = 0; c < 2; c++)
                    an[i][c] = *(const bf16x8*)(Ab + ((size_t)i * KC + kc0 + 2 + c) * 512);
            #pragma unroll
            for (int j = 0; j < 2; j++)
                #pragma unroll
                for (int c = 0; c < 2; c++)
                    bn[j][c] = *(const bf16x8*)(Bb + ((size_t)j * KC + kc0 + 2 + c) * 512);
        }
        #pragma unroll
        for (int c = 0; c < 2; c++)
            #pragma unroll
            for (int i = 0; i < 4; i++)
                #pragma unroll
                for (int j = 0; j < 2; j++)
                    acc[i][j] = __builtin_amdgcn_mfma_f32_16x16x32_bf16(ac[i][c], bc[j][c], acc[i][j], 0, 0, 0);
        if (pre) {
            #pragma unroll
            for (int i = 0; i < 4; i++)
                #pragma unroll
                for (int c = 0; c < 2; c++) ac[i][c] = an[i][c];
            #pragma unroll
            for (int j = 0; j < 2; j++)
                #pragma unroll
                for (int c = 0; c < 2; c++) bc[j][c] = bn[j][c];
        }
    }

    #pragma unroll
    for (int i = 0; i < 4; i++)
        #pragma unroll
        for (int j = 0; j < 2; j++) {
            int mbase = m0 + wm + i * 16 + quad * 4;
            int n     = n0 + wn + j * 16 + lm;
            float bsn = bias[n];
            #pragma unroll
            for (int r = 0; r < 4; r++) {
                size_t idx = (size_t)(mbase + r) * N + n;
                out[idx] = acc[i][j][r] + bsn + add[idx];
            }
        }
}

// ---------------------------------------------------------------------------
// Flash attention, MFMA, S^T formulation — 8 waves x 16 q-rows (512 thr).
// Q pre-scaled by 1/sqrt(64); wave-uniform branch isolates the single
// diagonal (masked) tile per wave. Output in FRAG ORDER for gemm_direct.
// ---------------------------------------------------------------------------
#define QT_ 128
#define KT_ 64

__global__ __launch_bounds__(512) void attn_mfma_kernel(const bf16* __restrict__ qkv,
                                                        bf16* __restrict__ of) {
    int bh = blockIdx.x;
    int b = bh >> 4, h = bh & 15;
    int q0 = (gridDim.y - 1 - blockIdx.y) * QT_;   // heavy-first
    int tid = threadIdx.x, wid = tid >> 6, lane = tid & 63;
    int lm = lane & 15, quad = lane >> 4;
    int sw = lm & 7;
    int r0 = q0 + wid * 16;                        // this wave's 16 q-rows

    const bf16* base = qkv + (size_t)b * T_ * (3 * C_) + h * (3 * HD_);

    __shared__ __align__(16) bf16 Ks[KT_][72];      // K rows [key][d]
    __shared__ __align__(16) bf16 Vt[HD_][72];      // V^T [d][key-swizzled]
    __shared__ __align__(16) bf16 PsT[8][16][64];   // per-wave P [qrow][key-swizzled]

    // Q fragment (B-operand: lane lm = q-row), pre-scaled by 1/sqrt(HD)=0.125
    bf16x8 qf[2];
    #pragma unroll
    for (int kc = 0; kc < 2; kc++) {
        bf16x8 t = *(const bf16x8*)(base + (size_t)(r0 + lm) * (3 * C_) + kc * 32 + quad * 8);
        #pragma unroll
        for (int e = 0; e < 8; e++) t[e] = (bf16)((float)t[e] * 0.125f);
        qf[kc] = t;
    }

    floatx4 acc_o[4];
    #pragma unroll
    for (int dn = 0; dn < 4; dn++) { floatx4 z = {0.f, 0.f, 0.f, 0.f}; acc_o[dn] = z; }
    float mst = -1e30f, lst = 0.0f;

    int srow = tid >> 3;              // 0..63
    int scol = (tid & 7) * 8;

    int kmax = q0 + QT_;
    for (int k0 = 0; k0 < kmax; k0 += KT_) {
        bf16x8 kv = *(const bf16x8*)(base + (size_t)(k0 + srow) * (3 * C_) + HD_ + scol);
        bf16x8 vv = *(const bf16x8*)(base + (size_t)(k0 + srow) * (3 * C_) + 2 * HD_ + scol);
        __syncthreads();
        *(bf16x8*)(&Ks[srow][scol]) = kv;
        {
            int c = scol >> 3;
            int pk = ((srow >> 3) ^ c) * 8 + (srow & 7);
            #pragma unroll
            for (int j = 0; j < 8; j++) Vt[scol + j][pk] = vv[j];
        }
        __syncthreads();

        if (k0 <= r0 + 15) {
            // S^T: rows = keys (4 tiles), cols = this wave's 16 q-rows
            floatx4 st[4];
            #pragma unroll
            for (int bn = 0; bn < 4; bn++) { floatx4 z = {0.f, 0.f, 0.f, 0.f}; st[bn] = z; }
            #pragma unroll
            for (int kc = 0; kc < 2; kc++) {
                bf16x8 kf[4];
                #pragma unroll
                for (int bn = 0; bn < 4; bn++)
                    kf[bn] = *(const bf16x8*)(&Ks[bn * 16 + lm][kc * 32 + quad * 8]);
                #pragma unroll
                for (int bn = 0; bn < 4; bn++)
                    st[bn] = __builtin_amdgcn_mfma_f32_16x16x32_bf16(kf[bn], qf[kc], st[bn], 0, 0, 0);
            }

            float vv_[4][4];
            float rm = -1e30f;
            if (k0 + KT_ - 1 > r0) {      // diagonal tile (wave-uniform branch)
                int gq = r0 + lm;
                #pragma unroll
                for (int bn = 0; bn < 4; bn++)
                    #pragma unroll
                    for (int r = 0; r < 4; r++) {
                        int key = k0 + bn * 16 + quad * 4 + r;
                        float sv = (key <= gq) ? st[bn][r] : -1e30f;
                        vv_[bn][r] = sv;
                        rm = fmaxf(rm, sv);
                    }
            } else {
                #pragma unroll
                for (int bn = 0; bn < 4; bn++)
                    #pragma unroll
                    for (int r = 0; r < 4; r++) {
                        vv_[bn][r] = st[bn][r];
                        rm = fmaxf(rm, st[bn][r]);
                    }
            }
            rm = fmaxf(rm, __shfl_xor(rm, 16));
            rm = fmaxf(rm, __shfl_xor(rm, 32));
            float mnew = fmaxf(mst, rm);
            float alpha = __expf(mst - mnew);
            mst = mnew;
            float ps = 0.f;
            #pragma unroll
            for (int bn = 0; bn < 4; bn++) {
                float p0 = __expf(vv_[bn][0] - mnew);
                float p1 = __expf(vv_[bn][1] - mnew);
                float p2 = __expf(vv_[bn][2] - mnew);
                float p3 = __expf(vv_[bn][3] - mnew);
                ps += (p0 + p1) + (p2 + p3);
                bf16x4 pk = { (bf16)p0, (bf16)p1, (bf16)p2, (bf16)p3 };
                int kb = bn * 2 + (quad >> 1);
                int col = ((kb ^ sw) << 3) + (quad & 1) * 4;
                *(bf16x4*)(&PsT[wid][lm][col]) = pk;
            }
            ps += __shfl_xor(ps, 16);
            ps += __shfl_xor(ps, 32);
            lst = lst * alpha + ps;

            #pragma unroll
            for (int r = 0; r < 4; r++) {
                float ar = __shfl(alpha, quad * 4 + r);
                #pragma unroll
                for (int dn = 0; dn < 4; dn++) acc_o[dn][r] *= ar;
            }

            __asm__ volatile("s_waitcnt lgkmcnt(0)" ::: "memory");

            #pragma unroll
            for (int kc = 0; kc < 2; kc++) {
                bf16x8 pa = *(const bf16x8*)(&PsT[wid][lm][((kc * 4 + quad) ^ sw) << 3]);
                bf16x8 vfr[4];
                #pragma unroll
                for (int dn = 0; dn < 4; dn++) {
                    int d = dn * 16 + lm;
                    int swd = (d >> 3) & 7;
                    vfr[dn] = *(const bf16x8*)(&Vt[d][(((kc * 4 + quad) ^ swd) << 3)]);
                }
                #pragma unroll
                for (int dn = 0; dn < 4; dn++)
                    acc_o[dn] = __builtin_amdgcn_mfma_f32_16x16x32_bf16(pa, vfr[dn], acc_o[dn], 0, 0, 0);
            }
        }
    }

    // epilogue: normalize, stage C->A-frag via per-wave PsT, frag-order store
    float il = 1.0f / lst;
    #pragma unroll
    for (int r = 0; r < 4; r++) {
        float ir = __shfl(il, quad * 4 + r);
        #pragma unroll
        for (int dn = 0; dn < 4; dn++)
            PsT[wid][quad * 4 + r][dn * 16 + lm] = (bf16)(acc_o[dn][r] * ir);
    }
    __asm__ volatile("s_waitcnt lgkmcnt(0)" ::: "memory");
    size_t mtb = ((size_t)b * T_ + r0) >> 4;
    #pragma unroll
    for (int kcl = 0; kcl < 2; kcl++) {
        bf16x8 v = *(const bf16x8*)&PsT[wid][lm][kcl * 32 + quad * 8];
        *(bf16x8*)(of + (mtb * (C_ >> 5) + (h * 2 + kcl)) * 512 + lane * 8) = v;
    }
}

// ---------------------------------------------------------------------------
extern "C" void kernel_launch(void* const* d_in, const int* in_sizes, int n_in,
                              void* d_out, int out_size, void* d_ws, size_t ws_size,
                              hipStream_t stream) {
    (void)in_sizes; (void)n_in; (void)out_size; (void)ws_size;
    const float* x      = (const float*)d_in[0];
    const float* ln1_g  = (const float*)d_in[1];
    const float* ln1_b  = (const float*)d_in[2];
    const float* ln2_g  = (const float*)d_in[3];
    const float* ln2_b  = (const float*)d_in[4];
    const float* w_in   = (const float*)d_in[5];
    const float* b_in   = (const float*)d_in[6];
    const float* w_out  = (const float*)d_in[7];
    const float* b_out  = (const float*)d_in[8];
    const float* w_fc   = (const float*)d_in[9];
    const float* b_fc   = (const float*)d_in[10];
    const float* w_proj = (const float*)d_in[11];
    const float* b_proj = (const float*)d_in[12];

    char* ws = (char*)d_ws;
    const size_t MB = 1024 * 1024;
    bf16*  w_inT   = (bf16*)(ws + 0);        // 6 MB row-major (N,K)
    bf16*  w_outF  = (bf16*)(ws + 6 * MB);   // 2 MB frag
    bf16*  w_fcT   = (bf16*)(ws + 8 * MB);   // 8 MB row-major (N,K)
    bf16*  w_projF = (bf16*)(ws + 16 * MB);  // 8 MB frag
    bf16*  qkv     = (bf16*)(ws + 24 * MB);  // 24 MB (shares 32MB region with fc_frag)
    bf16*  fc_frag = (bf16*)(ws + 24 * MB);  // 32 MB frag
    bf16*  o_frag  = (bf16*)(ws + 56 * MB);  // 8 MB frag (shares with y_b)
    bf16*  y_b     = (bf16*)(ws + 56 * MB);  // 8 MB
    bf16*  h_b     = (bf16*)(ws + 64 * MB);  // 8 MB (shares 16MB region with x1)
    float* x1      = (float*)(ws + 64 * MB); // 16 MB
    float* y_f     = (float*)(ws + 80 * MB); // 16 MB

    const int M = B_ * T_;  // 4096

    transpose_all<<<9728, 256, 0, stream>>>(w_in, w_out, w_fc, w_proj,
                                            w_inT, w_outF, w_fcT, w_projF);

    ln_kernel<<<M, 256, 0, stream>>>(x, ln1_g, ln1_b, h_b, nullptr);
    gemm128<0><<<dim3(3 * C_ / 128, M / 128), 256, 0, stream>>>(h_b, w_inT, b_in,
                                                                qkv, M, 3 * C_, C_);
    attn_mfma_kernel<<<dim3(B_ * H_, T_ / QT_), 512, 0, stream>>>(qkv, o_frag);
    gemm_direct<<<512, 256, 0, stream>>>(o_frag, w_outF, b_out, x, x1, M, C_, C_);
    ln_kernel<<<M, 256, 0, stream>>>(x1, ln2_g, ln2_b, y_b, y_f);
    gemm128<1><<<dim3(4 * C_ / 128, M / 128), 256, 0, stream>>>(y_b, w_fcT, b_fc,
                                                                fc_frag, M, 4 * C_, C_);
    gemm_direct<<<512, 256, 0, stream>>>(fc_frag, w_projF, b_proj, y_f,
                                         (float*)d_out, M, C_, 4 * C_);
}

// Round 9
// 338.003 us; speedup vs baseline: 1.2839x; 1.0486x over previous
//
#include <hip/hip_runtime.h>
#include <hip/hip_bf16.h>
#include <math.h>

typedef __bf16 bf16;
typedef __bf16 bf16x8 __attribute__((ext_vector_type(8)));
typedef __bf16 bf16x4 __attribute__((ext_vector_type(4)));
typedef float floatx4 __attribute__((ext_vector_type(4)));

#define B_ 2
#define T_ 2048
#define C_ 1024
#define H_ 16
#define HD_ 64

// Fragment-order layout for a GEMM operand X[R][Kd] (both A and B sides):
//   tile (rt = r>>4, kc = k>>5), tile base = (rt*(Kd>>5)+kc)*512 elements,
//   within tile: lane = (r&15) + 16*((k>>3)&3), elem = k&7  -> lane*8+elem.

// async global->LDS, 16B per lane; lds dest = uniform base + lane*16
__device__ __forceinline__ void gload_lds16(const bf16* g, bf16* l) {
    __builtin_amdgcn_global_load_lds(
        (const __attribute__((address_space(1))) unsigned int*)(g),
        (__attribute__((address_space(3))) unsigned int*)(l), 16, 0, 0);
}

// ---------------------------------------------------------------------------
// All weight preprocessing in ONE launch (see R7 notes).
// ---------------------------------------------------------------------------
__global__ __launch_bounds__(256) void transpose_all(
        const float* __restrict__ w_in, const float* __restrict__ w_out,
        const float* __restrict__ w_fc, const float* __restrict__ w_proj,
        bf16* __restrict__ o_in, bf16* __restrict__ o_out,
        bf16* __restrict__ o_fc, bf16* __restrict__ o_proj) {
    __shared__ float shf[64 * 33];
    int t = blockIdx.x;
    int tid = threadIdx.x;
    if (t < 7168) {
        const float* src; bf16* dst; int K, N, idx;
        if (t < 3072) { src = w_in; dst = o_in; K = 1024; N = 3072; idx = t; }
        else          { src = w_fc; dst = o_fc; K = 1024; N = 4096; idx = t - 3072; }
        int ntx = N >> 5;
        int nt = (idx % ntx) * 32, kt = (idx / ntx) * 32;
        int tx = tid & 31, ty = tid >> 5;  // 32 x 8
        #pragma unroll
        for (int i = 0; i < 32; i += 8)
            shf[(ty + i) * 33 + tx] = src[(size_t)(kt + ty + i) * N + nt + tx];
        __syncthreads();
        #pragma unroll
        for (int i = 0; i < 32; i += 8)
            dst[(size_t)(nt + ty + i) * K + kt + tx] = (bf16)shf[tx * 33 + ty + i];
    } else {
        const float* src; bf16* dst; int K, idx;
        if (t < 7680) { src = w_out;  dst = o_out;  K = 1024; idx = t - 7168; }
        else          { src = w_proj; dst = o_proj; K = 4096; idx = t - 7680; }
        const int N = 1024;
        int n0 = (idx & 31) * 32, k0 = (idx >> 5) * 64;
        int col = tid & 31, kr = tid >> 5;
        #pragma unroll
        for (int s = 0; s < 8; s++)
            shf[(kr + s * 8) * 33 + col] = src[(size_t)(k0 + kr + s * 8) * N + n0 + col];
        __syncthreads();
        int tl = tid >> 6, l = tid & 63;
        int ntl = tl & 1, kcl = tl >> 1;
        int rr = ntl * 16 + (l & 15);
        int qd = l >> 4;
        bf16x8 v;
        #pragma unroll
        for (int e = 0; e < 8; e++)
            v[e] = (bf16)shf[(kcl * 32 + qd * 8 + e) * 33 + rr];
        size_t nt_g = (n0 >> 4) + ntl, kc_g = (k0 >> 5) + kcl;
        *(bf16x8*)(dst + (nt_g * (K >> 5) + kc_g) * 512 + l * 8) = v;
    }
}

// ---------------------------------------------------------------------------
// LayerNorm over C=1024. One block (256 threads) per row; 4 floats/thread.
// ---------------------------------------------------------------------------
__global__ __launch_bounds__(256) void ln_kernel(const float* __restrict__ x,
                                                 const float* __restrict__ g,
                                                 const float* __restrict__ b,
                                                 bf16* __restrict__ out_b,
                                                 float* __restrict__ out_f) {
    int row = blockIdx.x;
    int tid = threadIdx.x;
    const float* xr = x + (size_t)row * C_;
    float4 v = ((const float4*)xr)[tid];
    float s  = v.x + v.y + v.z + v.w;
    float ss = v.x * v.x + v.y * v.y + v.z * v.z + v.w * v.w;
    #pragma unroll
    for (int off = 32; off; off >>= 1) {
        s  += __shfl_down(s, off);
        ss += __shfl_down(ss, off);
    }
    __shared__ float red[8];
    int wid = tid >> 6;
    if ((tid & 63) == 0) { red[wid] = s; red[wid + 4] = ss; }
    __syncthreads();
    s  = red[0] + red[1] + red[2] + red[3];
    ss = red[4] + red[5] + red[6] + red[7];
    float mean = s * (1.0f / C_);
    float var  = ss * (1.0f / C_) - mean * mean;
    float rstd = rsqrtf(var + 1e-5f);
    float4 gv = ((const float4*)g)[tid];
    float4 bv = ((const float4*)b)[tid];
    float o0 = (v.x - mean) * rstd * gv.x + bv.x;
    float o1 = (v.y - mean) * rstd * gv.y + bv.y;
    float o2 = (v.z - mean) * rstd * gv.z + bv.z;
    float o3 = (v.w - mean) * rstd * gv.w + bv.w;
    bf16x4 ob = { (bf16)o0, (bf16)o1, (bf16)o2, (bf16)o3 };
    ((bf16x4*)out_b)[(size_t)row * 256 + tid] = ob;
    if (out_f) {
        float4 of; of.x = o0; of.y = o1; of.z = o2; of.w = o3;
        ((float4*)out_f)[(size_t)row * 256 + tid] = of;
    }
}

// ---------------------------------------------------------------------------
// Wide GEMM, m97 structure + XOR-swizzled LDS staging (conflict-free frag
// reads: unit (row,cb) at row*8 + (cb ^ (row&7)); staging lane fetches
// global colblock (lane&7)^(lane>>3) so global_load_lds' fixed lane*16 dest
// realizes the swizzle). 128x128 tile, 256 thr = 4 waves.
// MODE 0: +bias, bf16 row-major out (qkv).
// MODE 1: +bias+gelu(tanh-form), bf16 FRAG-ORDER out via 128x68 LDS stage.
// ---------------------------------------------------------------------------
__device__ __forceinline__ float gelu_fast(float x) {
    // tanh-form GELU, |err| vs exact erf form < ~1e-3 (output slack ~0.10)
    float z2 = 1.5957691216f * (x + 0.044715f * x * x * x);   // 2*0.79788456*(x+..)
    float e = __expf(z2);
    float t = 1.0f - 2.0f * __builtin_amdgcn_rcpf(e + 1.0f);  // tanh(z)
    return 0.5f * x * (1.0f + t);
}

template<int MODE>
__global__ __launch_bounds__(256) void gemm128(const bf16* __restrict__ A,
                                               const bf16* __restrict__ Bt,
                                               const float* __restrict__ bias,
                                               void* __restrict__ out,
                                               int M, int N, int K) {
    __shared__ __align__(16) bf16 smem[2 * 128 * 64];   // 32 KB: As|Bs, reused by epilogue
    bf16* As = smem;
    bf16* Bs = smem + 128 * 64;

    int m0 = blockIdx.y * 128, n0 = blockIdx.x * 128;
    int tid = threadIdx.x;
    int wid = __builtin_amdgcn_readfirstlane(tid >> 6);
    int lane = tid & 63;
    int lm = lane & 15, quad = lane >> 4;
    int wm = (wid & 1) * 64;
    int wn = (wid >> 1) * 64;
    int lrow = lane >> 3;                     // 0..7
    int lcol = (((lane & 7) ^ lrow)) * 8;     // xor-swizzled source colblock

    const bf16* Ablk = A  + (size_t)m0 * K;
    const bf16* Bblk = Bt + (size_t)n0 * K;

    floatx4 acc[4][4];
    #pragma unroll
    for (int i = 0; i < 4; i++)
        #pragma unroll
        for (int j = 0; j < 4; j++) { floatx4 z = {0.f, 0.f, 0.f, 0.f}; acc[i][j] = z; }

    for (int k0 = 0; k0 < K; k0 += 64) {
        __syncthreads();
        #pragma unroll
        for (int c = 0; c < 4; c++) {
            int row = wid * 32 + c * 8;
            gload_lds16(Ablk + (size_t)(row + lrow) * K + k0 + lcol, As + row * 64);
        }
        #pragma unroll
        for (int c = 0; c < 4; c++) {
            int row = wid * 32 + c * 8;
            gload_lds16(Bblk + (size_t)(row + lrow) * K + k0 + lcol, Bs + row * 64);
        }
        __syncthreads();
        #pragma unroll
        for (int kc = 0; kc < 2; kc++) {
            bf16x8 af[4], bfr[4];
            #pragma unroll
            for (int i = 0; i < 4; i++)
                af[i] = *(const bf16x8*)(As + (wm + i * 16 + lm) * 64 +
                                         ((((kc << 2) + quad) ^ (lm & 7)) << 3));
            #pragma unroll
            for (int j = 0; j < 4; j++)
                bfr[j] = *(const bf16x8*)(Bs + (wn + j * 16 + lm) * 64 +
                                          ((((kc << 2) + quad) ^ (lm & 7)) << 3));
            #pragma unroll
            for (int i = 0; i < 4; i++)
                #pragma unroll
                for (int j = 0; j < 4; j++)
                    acc[i][j] = __builtin_amdgcn_mfma_f32_16x16x32_bf16(af[i], bfr[j], acc[i][j], 0, 0, 0);
        }
    }

    if (MODE == 0) {
        #pragma unroll
        for (int i = 0; i < 4; i++)
            #pragma unroll
            for (int j = 0; j < 4; j++) {
                int mbase = m0 + wm + i * 16 + quad * 4;
                int n     = n0 + wn + j * 16 + lm;
                float bsn = bias[n];
                #pragma unroll
                for (int r = 0; r < 4; r++)
                    ((bf16*)out)[(size_t)(mbase + r) * N + n] = (bf16)(acc[i][j][r] + bsn);
            }
    } else {
        // frag-order out, two 64-col halves through a 128x68 stage (17 KB)
        bf16* ob = (bf16*)out;
        #pragma unroll
        for (int nh = 0; nh < 2; nh++) {
            __syncthreads();
            if ((wn >> 6) == nh) {
                #pragma unroll
                for (int i = 0; i < 4; i++)
                    #pragma unroll
                    for (int j = 0; j < 4; j++) {
                        int n = n0 + wn + j * 16 + lm;
                        float bsn = bias[n];
                        #pragma unroll
                        for (int r = 0; r < 4; r++)
                            smem[(wm + i * 16 + quad * 4 + r) * 68 + j * 16 + lm] =
                                (bf16)gelu_fast(acc[i][j][r] + bsn);
                    }
            }
            __syncthreads();
            #pragma unroll
            for (int p = 0; p < 4; p++) {
                int tl = wid * 4 + p;            // 0..15
                int mtl = tl >> 1, kclp = tl & 1;
                bf16x8 v = *(const bf16x8*)&smem[(mtl * 16 + lm) * 68 + kclp * 32 + quad * 8];
                int kcl = nh * 2 + kclp;
                *(bf16x8*)(ob + (((size_t)((m0 >> 4) + mtl) * (N >> 5) + (n0 >> 5) + kcl) * 512)
                           + lane * 8) = v;
            }
        }
    }
}

// ---------------------------------------------------------------------------
// Narrow-N GEMM, fully LDS-free: both operands in frag order, direct
// global->register loads, register double-buffer, NO barriers.
// 128x64 block tile, 4 waves (64x32 each). XCD-swizzled 1D grid.
// ---------------------------------------------------------------------------
__global__ __launch_bounds__(256) void gemm_direct(const bf16* __restrict__ Af,
                                                   const bf16* __restrict__ Bf,
                                                   const float* __restrict__ bias,
                                                   const float* __restrict__ add,
                                                   float* __restrict__ out,
                                                   int M, int N, int K) {
    int lin = blockIdx.x;
    int xcd = lin & 7, loc = lin >> 3;
    int m0 = ((xcd << 2) | (loc & 3)) * 128;
    int n0 = (loc >> 2) * 64;
    int tid = threadIdx.x;
    int wid = __builtin_amdgcn_readfirstlane(tid >> 6);
    int lane = tid & 63;
    int lm = lane & 15, quad = lane >> 4;
    int wm = (wid & 1) * 64, wn = (wid >> 1) * 32;
    int KC = K >> 5;
    const bf16* Ab = Af + ((size_t)((m0 + wm) >> 4) * KC) * 512 + lane * 8;
    const bf16* Bb = Bf + ((size_t)((n0 + wn) >> 4) * KC) * 512 + lane * 8;

    floatx4 acc[4][2];
    #pragma unroll
    for (int i = 0; i < 4; i++)
        #pragma unroll
        for (int j = 0; j < 2; j++) { floatx4 z = {0.f, 0.f, 0.f, 0.f}; acc[i][j] = z; }

    bf16x8 ac[4][2], bc[2][2], an[4][2], bn[2][2];
    #pragma unroll
    for (int i = 0; i < 4; i++)
        #pragma unroll
        for (int c = 0; c < 2; c++)
            ac[i][c] = *(const bf16x8*)(Ab + ((size_t)i * KC + c) * 512);
    #pragma unroll
    for (int j = 0; j < 2; j++)
        #pragma unroll
        for (int c = 0; c < 2; c++)
            bc[j][c] = *(const bf16x8*)(Bb + ((size_t)j * KC + c) * 512);

    for (int kc0 = 0; kc0 < KC; kc0 += 2) {
        bool pre = (kc0 + 2) < KC;
        if (pre) {
            #pragma unroll
            for (int i = 0; i < 4; i++)
                #pragma unroll
                for (int c = 0; c < 2; c++)
                    an[i][c] = *(const bf16x8*)(Ab + ((size_t)i * KC + kc0 + 2 + c) * 512);
            #pragma unroll
            for (int j = 0; j < 2; j++)
                #pragma unroll
                for (int c = 0; c < 2; c++)
                    bn[j][c] = *(const bf16x8*)(Bb + ((size_t)j * KC + kc0 + 2 + c) * 512);
        }
        #pragma unroll
        for (int c = 0; c < 2; c++)
            #pragma unroll
            for (int i = 0; i < 4; i++)
                #pragma unroll
                for (int j = 0; j < 2; j++)
                    acc[i][j] = __builtin_amdgcn_mfma_f32_16x16x32_bf16(ac[i][c], bc[j][c], acc[i][j], 0, 0, 0);
        if (pre) {
            #pragma unroll
            for (int i = 0; i < 4; i++)
                #pragma unroll
                for (int c = 0; c < 2; c++) ac[i][c] = an[i][c];
            #pragma unroll
            for (int j = 0; j < 2; j++)
                #pragma unroll
                for (int c = 0; c < 2; c++) bc[j][c] = bn[j][c];
        }
    }

    #pragma unroll
    for (int i = 0; i < 4; i++)
        #pragma unroll
        for (int j = 0; j < 2; j++) {
            int mbase = m0 + wm + i * 16 + quad * 4;
            int n     = n0 + wn + j * 16 + lm;
            float bsn = bias[n];
            #pragma unroll
            for (int r = 0; r < 4; r++) {
                size_t idx = (size_t)(mbase + r) * N + n;
                out[idx] = acc[i][j][r] + bsn + add[idx];
            }
        }
}

// ---------------------------------------------------------------------------
// Flash attention, MFMA, S^T formulation — 8 waves x 16 q-rows (512 thr).
// Q pre-scaled by 1/sqrt(64); wave-uniform diagonal-tile branch.
// Output in FRAG ORDER for gemm_direct.
// ---------------------------------------------------------------------------
#define QT_ 128
#define KT_ 64

__global__ __launch_bounds__(512) void attn_mfma_kernel(const bf16* __restrict__ qkv,
                                                        bf16* __restrict__ of) {
    int bh = blockIdx.x;
    int b = bh >> 4, h = bh & 15;
    int q0 = (gridDim.y - 1 - blockIdx.y) * QT_;   // heavy-first
    int tid = threadIdx.x, wid = tid >> 6, lane = tid & 63;
    int lm = lane & 15, quad = lane >> 4;
    int sw = lm & 7;
    int r0 = q0 + wid * 16;                        // this wave's 16 q-rows

    const bf16* base = qkv + (size_t)b * T_ * (3 * C_) + h * (3 * HD_);

    __shared__ __align__(16) bf16 Ks[KT_][72];      // K rows [key][d]
    __shared__ __align__(16) bf16 Vt[HD_][72];      // V^T [d][key-swizzled]
    __shared__ __align__(16) bf16 PsT[8][16][64];   // per-wave P [qrow][key-swizzled]

    bf16x8 qf[2];
    #pragma unroll
    for (int kc = 0; kc < 2; kc++) {
        bf16x8 t = *(const bf16x8*)(base + (size_t)(r0 + lm) * (3 * C_) + kc * 32 + quad * 8);
        #pragma unroll
        for (int e = 0; e < 8; e++) t[e] = (bf16)((float)t[e] * 0.125f);
        qf[kc] = t;
    }

    floatx4 acc_o[4];
    #pragma unroll
    for (int dn = 0; dn < 4; dn++) { floatx4 z = {0.f, 0.f, 0.f, 0.f}; acc_o[dn] = z; }
    float mst = -1e30f, lst = 0.0f;

    int srow = tid >> 3;              // 0..63
    int scol = (tid & 7) * 8;

    int kmax = q0 + QT_;
    for (int k0 = 0; k0 < kmax; k0 += KT_) {
        bf16x8 kv = *(const bf16x8*)(base + (size_t)(k0 + srow) * (3 * C_) + HD_ + scol);
        bf16x8 vv = *(const bf16x8*)(base + (size_t)(k0 + srow) * (3 * C_) + 2 * HD_ + scol);
        __syncthreads();
        *(bf16x8*)(&Ks[srow][scol]) = kv;
        {
            int c = scol >> 3;
            int pk = ((srow >> 3) ^ c) * 8 + (srow & 7);
            #pragma unroll
            for (int j = 0; j < 8; j++) Vt[scol + j][pk] = vv[j];
        }
        __syncthreads();

        if (k0 <= r0 + 15) {
            floatx4 st[4];
            #pragma unroll
            for (int bn = 0; bn < 4; bn++) { floatx4 z = {0.f, 0.f, 0.f, 0.f}; st[bn] = z; }
            #pragma unroll
            for (int kc = 0; kc < 2; kc++) {
                bf16x8 kf[4];
                #pragma unroll
                for (int bn = 0; bn < 4; bn++)
                    kf[bn] = *(const bf16x8*)(&Ks[bn * 16 + lm][kc * 32 + quad * 8]);
                #pragma unroll
                for (int bn = 0; bn < 4; bn++)
                    st[bn] = __builtin_amdgcn_mfma_f32_16x16x32_bf16(kf[bn], qf[kc], st[bn], 0, 0, 0);
            }

            float vv_[4][4];
            float rm = -1e30f;
            if (k0 + KT_ - 1 > r0) {      // diagonal tile (wave-uniform branch)
                int gq = r0 + lm;
                #pragma unroll
                for (int bn = 0; bn < 4; bn++)
                    #pragma unroll
                    for (int r = 0; r < 4; r++) {
                        int key = k0 + bn * 16 + quad * 4 + r;
                        float sv = (key <= gq) ? st[bn][r] : -1e30f;
                        vv_[bn][r] = sv;
                        rm = fmaxf(rm, sv);
                    }
            } else {
                #pragma unroll
                for (int bn = 0; bn < 4; bn++)
                    #pragma unroll
                    for (int r = 0; r < 4; r++) {
                        vv_[bn][r] = st[bn][r];
                        rm = fmaxf(rm, st[bn][r]);
                    }
            }
            rm = fmaxf(rm, __shfl_xor(rm, 16));
            rm = fmaxf(rm, __shfl_xor(rm, 32));
            float mnew = fmaxf(mst, rm);
            float alpha = __expf(mst - mnew);
            mst = mnew;
            float ps = 0.f;
            #pragma unroll
            for (int bn = 0; bn < 4; bn++) {
                float p0 = __expf(vv_[bn][0] - mnew);
                float p1 = __expf(vv_[bn][1] - mnew);
                float p2 = __expf(vv_[bn][2] - mnew);
                float p3 = __expf(vv_[bn][3] - mnew);
                ps += (p0 + p1) + (p2 + p3);
                bf16x4 pk = { (bf16)p0, (bf16)p1, (bf16)p2, (bf16)p3 };
                int kb = bn * 2 + (quad >> 1);
                int col = ((kb ^ sw) << 3) + (quad & 1) * 4;
                *(bf16x4*)(&PsT[wid][lm][col]) = pk;
            }
            ps += __shfl_xor(ps, 16);
            ps += __shfl_xor(ps, 32);
            lst = lst * alpha + ps;

            #pragma unroll
            for (int r = 0; r < 4; r++) {
                float ar = __shfl(alpha, quad * 4 + r);
                #pragma unroll
                for (int dn = 0; dn < 4; dn++) acc_o[dn][r] *= ar;
            }

            __asm__ volatile("s_waitcnt lgkmcnt(0)" ::: "memory");

            #pragma unroll
            for (int kc = 0; kc < 2; kc++) {
                bf16x8 pa = *(const bf16x8*)(&PsT[wid][lm][((kc * 4 + quad) ^ sw) << 3]);
                bf16x8 vfr[4];
                #pragma unroll
                for (int dn = 0; dn < 4; dn++) {
                    int d = dn * 16 + lm;
                    int swd = (d >> 3) & 7;
                    vfr[dn] = *(const bf16x8*)(&Vt[d][(((kc * 4 + quad) ^ swd) << 3)]);
                }
                #pragma unroll
                for (int dn = 0; dn < 4; dn++)
                    acc_o[dn] = __builtin_amdgcn_mfma_f32_16x16x32_bf16(pa, vfr[dn], acc_o[dn], 0, 0, 0);
            }
        }
    }

    float il = 1.0f / lst;
    #pragma unroll
    for (int r = 0; r < 4; r++) {
        float ir = __shfl(il, quad * 4 + r);
        #pragma unroll
        for (int dn = 0; dn < 4; dn++)
            PsT[wid][quad * 4 + r][dn * 16 + lm] = (bf16)(acc_o[dn][r] * ir);
    }
    __asm__ volatile("s_waitcnt lgkmcnt(0)" ::: "memory");
    size_t mtb = ((size_t)b * T_ + r0) >> 4;
    #pragma unroll
    for (int kcl = 0; kcl < 2; kcl++) {
        bf16x8 v = *(const bf16x8*)&PsT[wid][lm][kcl * 32 + quad * 8];
        *(bf16x8*)(of + (mtb * (C_ >> 5) + (h * 2 + kcl)) * 512 + lane * 8) = v;
    }
}

// ---------------------------------------------------------------------------
extern "C" void kernel_launch(void* const* d_in, const int* in_sizes, int n_in,
                              void* d_out, int out_size, void* d_ws, size_t ws_size,
                              hipStream_t stream) {
    (void)in_sizes; (void)n_in; (void)out_size; (void)ws_size;
    const float* x      = (const float*)d_in[0];
    const float* ln1_g  = (const float*)d_in[1];
    const float* ln1_b  = (const float*)d_in[2];
    const float* ln2_g  = (const float*)d_in[3];
    const float* ln2_b  = (const float*)d_in[4];
    const float* w_in   = (const float*)d_in[5];
    const float* b_in   = (const float*)d_in[6];
    const float* w_out  = (const float*)d_in[7];
    const float* b_out  = (const float*)d_in[8];
    const float* w_fc   = (const float*)d_in[9];
    const float* b_fc   = (const float*)d_in[10];
    const float* w_proj = (const float*)d_in[11];
    const float* b_proj = (const float*)d_in[12];

    char* ws = (char*)d_ws;
    const size_t MB = 1024 * 1024;
    bf16*  w_inT   = (bf16*)(ws + 0);        // 6 MB row-major (N,K)
    bf16*  w_outF  = (bf16*)(ws + 6 * MB);   // 2 MB frag
    bf16*  w_fcT   = (bf16*)(ws + 8 * MB);   // 8 MB row-major (N,K)
    bf16*  w_projF = (bf16*)(ws + 16 * MB);  // 8 MB frag
    bf16*  qkv     = (bf16*)(ws + 24 * MB);  // 24 MB (shares 32MB region with fc_frag)
    bf16*  fc_frag = (bf16*)(ws + 24 * MB);  // 32 MB frag
    bf16*  o_frag  = (bf16*)(ws + 56 * MB);  // 8 MB frag (shares with y_b)
    bf16*  y_b     = (bf16*)(ws + 56 * MB);  // 8 MB
    bf16*  h_b     = (bf16*)(ws + 64 * MB);  // 8 MB (shares 16MB region with x1)
    float* x1      = (float*)(ws + 64 * MB); // 16 MB
    float* y_f     = (float*)(ws + 80 * MB); // 16 MB

    const int M = B_ * T_;  // 4096

    transpose_all<<<9728, 256, 0, stream>>>(w_in, w_out, w_fc, w_proj,
                                            w_inT, w_outF, w_fcT, w_projF);

    ln_kernel<<<M, 256, 0, stream>>>(x, ln1_g, ln1_b, h_b, nullptr);
    gemm128<0><<<dim3(3 * C_ / 128, M / 128), 256, 0, stream>>>(h_b, w_inT, b_in,
                                                                qkv, M, 3 * C_, C_);
    attn_mfma_kernel<<<dim3(B_ * H_, T_ / QT_), 512, 0, stream>>>(qkv, o_frag);
    gemm_direct<<<512, 256, 0, stream>>>(o_frag, w_outF, b_out, x, x1, M, C_, C_);
    ln_kernel<<<M, 256, 0, stream>>>(x1, ln2_g, ln2_b, y_b, y_f);
    gemm128<1><<<dim3(4 * C_ / 128, M / 128), 256, 0, stream>>>(y_b, w_fcT, b_fc,
                                                                fc_frag, M, 4 * C_, C_);
    gemm_direct<<<512, 256, 0, stream>>>(fc_frag, w_projF, b_proj, y_f,
                                         (float*)d_out, M, C_, 4 * C_);
}